// Round 1
// baseline (2183.012 us; speedup 1.0000x reference)
//
#include <hip/hip_runtime.h>
#include <math.h>

#define NN 20000
#define EE 320000
#define ETOT (EE + NN)   // 340000 edges incl. self loops

// ---------------- CSR build ----------------
__global__ void deg_kernel(const int* __restrict__ ei, int* __restrict__ deg) {
  int e = blockIdx.x * 256 + threadIdx.x;
  if (e >= ETOT) return;
  int dst = (e < EE) ? ei[EE + e] : (e - EE);
  atomicAdd(&deg[dst], 1);
}

// single-block exclusive scan of deg[NN] -> rowptr[NN+1]
__global__ void scan_kernel(const int* __restrict__ deg, int* __restrict__ rowptr) {
  __shared__ int wsum[16];
  __shared__ int carry_s;
  const int tid = threadIdx.x;           // blockDim = 1024
  const int lane = tid & 63, wid = tid >> 6;
  if (tid == 0) carry_s = 0;
  __syncthreads();
  for (int base = 0; base < NN; base += 1024) {
    int i = base + tid;
    int v = (i < NN) ? deg[i] : 0;
    int x = v;
    #pragma unroll
    for (int off = 1; off < 64; off <<= 1) {
      int y = __shfl_up(x, off, 64);
      if (lane >= off) x += y;
    }
    if (lane == 63) wsum[wid] = x;
    __syncthreads();
    if (tid < 64) {
      int w = (tid < 16) ? wsum[tid] : 0;
      #pragma unroll
      for (int off = 1; off < 16; off <<= 1) {
        int y = __shfl_up(w, off, 64);
        if (lane >= off) w += y;
      }
      if (tid < 16) wsum[tid] = w;   // inclusive prefix of wave sums
    }
    __syncthreads();
    int incl = x + (wid > 0 ? wsum[wid - 1] : 0);
    int carry = carry_s;
    if (i < NN) rowptr[i] = carry + incl - v;   // exclusive
    __syncthreads();
    if (tid == 1023) carry_s = carry + incl;    // chunk total
    __syncthreads();
  }
  if (tid == 0) rowptr[NN] = carry_s;
}

__global__ void fill_kernel(const int* __restrict__ ei, int* __restrict__ cursor,
                            int* __restrict__ csr_src, int* __restrict__ csr_dst) {
  int e = blockIdx.x * 256 + threadIdx.x;
  if (e >= ETOT) return;
  int src, dst;
  if (e < EE) { src = ei[e]; dst = ei[EE + e]; } else { src = dst = e - EE; }
  int slot = atomicAdd(&cursor[dst], 1);
  csr_src[slot] = src;
  csr_dst[slot] = dst;
}

// ---------------- dense linear: y[n][o] = b[o] + sum_i x[n][i]*W[o][i] ----------------
template<int K, int OUT>
__global__ void lin_kernel(const float* __restrict__ x, const float* __restrict__ W,
                           const float* __restrict__ b, float* __restrict__ y) {
  __shared__ float xs[K];
  int n = blockIdx.x;
  for (int i = threadIdx.x; i < K; i += OUT) xs[i] = x[(size_t)n * K + i];
  __syncthreads();
  int o = threadIdx.x;
  const float4* w  = reinterpret_cast<const float4*>(W + (size_t)o * K);
  const float4* xv = reinterpret_cast<const float4*>(xs);
  float acc = 0.f;
  #pragma unroll
  for (int i = 0; i < K / 4; ++i) {
    float4 wv = w[i], v = xv[i];
    acc += wv.x * v.x + wv.y * v.y + wv.z * v.z + wv.w * v.w;
  }
  y[(size_t)n * OUT + o] = acc + b[o];
}

// ---------------- per-edge attention score ----------------
// score[slot][h] = sum_c att[h][c] * leaky_relu(xl[src][h*C+c] + xr[dst][h*C+c], 0.2)
template<int H, int C>
__global__ void score_kernel(const float* __restrict__ xl, const float* __restrict__ xr,
                             const int* __restrict__ csr_src, const int* __restrict__ csr_dst,
                             const float* __restrict__ att, float* __restrict__ scores) {
  int id = blockIdx.x * 256 + threadIdx.x;
  if (id >= ETOT * H) return;
  int slot = id / H;
  int h = id - slot * H;
  int src = csr_src[slot], dst = csr_dst[slot];
  const float4* a = reinterpret_cast<const float4*>(xl + (size_t)src * (H * C) + h * C);
  const float4* bb = reinterpret_cast<const float4*>(xr + (size_t)dst * (H * C) + h * C);
  const float4* w = reinterpret_cast<const float4*>(att + h * C);
  float acc = 0.f;
  #pragma unroll
  for (int i = 0; i < C / 4; ++i) {
    float4 av = a[i], bv = bb[i], wv = w[i];
    float e0 = av.x + bv.x; e0 = (e0 > 0.f) ? e0 : 0.2f * e0;
    float e1 = av.y + bv.y; e1 = (e1 > 0.f) ? e1 : 0.2f * e1;
    float e2 = av.z + bv.z; e2 = (e2 > 0.f) ? e2 : 0.2f * e2;
    float e3 = av.w + bv.w; e3 = (e3 > 0.f) ? e3 : 0.2f * e3;
    acc += wv.x * e0 + wv.y * e1 + wv.z * e2 + wv.w * e3;
  }
  scores[slot * H + h] = acc;
}

// ---------------- per-node segment softmax + weighted aggregation (+bias, +BN+ELU) ----------------
// block = H waves of 64; wave h handles head h of node blockIdx.x
template<int H, int C, bool BN_ELU>
__global__ void agg_kernel(const float* __restrict__ scores, const float* __restrict__ xl,
                           const int* __restrict__ rowptr, const int* __restrict__ csr_src,
                           const float* __restrict__ bias,
                           const float* __restrict__ bn_g, const float* __restrict__ bn_b,
                           const float* __restrict__ bn_m, const float* __restrict__ bn_v,
                           float* __restrict__ out) {
  const int F = H * C;
  int n = blockIdx.x;
  int h = threadIdx.x >> 6;
  int lane = threadIdx.x & 63;
  int beg = rowptr[n], end = rowptr[n + 1];
  // phase 1: max over this node's in-edges, per head (wave-parallel)
  float m = -3.4e38f;
  for (int s = beg + lane; s < end; s += 64) m = fmaxf(m, scores[s * H + h]);
  #pragma unroll
  for (int off = 32; off; off >>= 1) m = fmaxf(m, __shfl_xor(m, off, 64));
  // denom
  float d = 0.f;
  for (int s = beg + lane; s < end; s += 64) d += expf(scores[s * H + h] - m);
  #pragma unroll
  for (int off = 32; off; off >>= 1) d += __shfl_xor(d, off, 64);
  d += 1e-16f;
  // phase 2: weighted gather of xl[src]
  if (lane < C) {
    int c = lane;
    float acc = 0.f;
    for (int s = beg; s < end; ++s) {
      float w = expf(scores[s * H + h] - m);
      acc += w * xl[(size_t)csr_src[s] * F + h * C + c];
    }
    float v = acc / d + bias[h * C + c];
    if (BN_ELU) {
      int ch = h * C + c;
      float sc = bn_g[ch] * rsqrtf(bn_v[ch] + 1e-5f);
      v = sc * (v - bn_m[ch]) + bn_b[ch];
      v = (v > 0.f) ? v : expm1f(v);
    }
    out[(size_t)n * F + h * C + c] = v;
  }
}

extern "C" void kernel_launch(void* const* d_in, const int* in_sizes, int n_in,
                              void* d_out, int out_size, void* d_ws, size_t ws_size,
                              hipStream_t stream) {
  (void)in_sizes; (void)n_in; (void)out_size; (void)ws_size;
  const float* x  = (const float*)d_in[0];
  const int*   ei = (const int*)d_in[1];
  const float *Wl1 = (const float*)d_in[2],  *bl1 = (const float*)d_in[3],
              *Wr1 = (const float*)d_in[4],  *br1 = (const float*)d_in[5],
              *att1 = (const float*)d_in[6], *bias1 = (const float*)d_in[7],
              *g1 = (const float*)d_in[8],   *be1 = (const float*)d_in[9],
              *m1 = (const float*)d_in[10],  *v1 = (const float*)d_in[11];
  const float *Wl2 = (const float*)d_in[12], *bl2 = (const float*)d_in[13],
              *Wr2 = (const float*)d_in[14], *br2 = (const float*)d_in[15],
              *att2 = (const float*)d_in[16], *bias2 = (const float*)d_in[17],
              *g2 = (const float*)d_in[18],  *be2 = (const float*)d_in[19],
              *m2 = (const float*)d_in[20],  *v2 = (const float*)d_in[21];
  const float *Wl3 = (const float*)d_in[22], *bl3 = (const float*)d_in[23],
              *Wr3 = (const float*)d_in[24], *br3 = (const float*)d_in[25],
              *att3 = (const float*)d_in[26], *bias3 = (const float*)d_in[27];
  float* out = (float*)d_out;

  char* p = (char*)d_ws;
  auto alloc = [&](size_t bytes) { char* r = p; p += (bytes + 255) & ~(size_t)255; return r; };
  int*   deg     = (int*)alloc((size_t)NN * 4);
  int*   rowptr  = (int*)alloc((size_t)(NN + 1) * 4);
  int*   cursor  = (int*)alloc((size_t)NN * 4);
  int*   csr_src = (int*)alloc((size_t)ETOT * 4);
  int*   csr_dst = (int*)alloc((size_t)ETOT * 4);
  float* scores  = (float*)alloc((size_t)ETOT * 4 * 4);
  float* xl      = (float*)alloc((size_t)NN * 256 * 4);
  float* xr      = (float*)alloc((size_t)NN * 256 * 4);
  float* hbuf    = (float*)alloc((size_t)NN * 256 * 4);

  // CSR by dst (rebuilt every call; deterministic set, order-insensitive within fp tolerance)
  hipMemsetAsync(deg, 0, (size_t)NN * 4, stream);
  deg_kernel<<<(ETOT + 255) / 256, 256, 0, stream>>>(ei, deg);
  scan_kernel<<<1, 1024, 0, stream>>>(deg, rowptr);
  hipMemcpyAsync(cursor, rowptr, (size_t)NN * 4, hipMemcpyDeviceToDevice, stream);
  fill_kernel<<<(ETOT + 255) / 256, 256, 0, stream>>>(ei, cursor, csr_src, csr_dst);

  // ---- layer 1: 4 -> 4x64 concat, BN+ELU ----
  lin_kernel<4, 256><<<NN, 256, 0, stream>>>(x, Wl1, bl1, xl);
  lin_kernel<4, 256><<<NN, 256, 0, stream>>>(x, Wr1, br1, xr);
  score_kernel<4, 64><<<(ETOT * 4 + 255) / 256, 256, 0, stream>>>(xl, xr, csr_src, csr_dst, att1, scores);
  agg_kernel<4, 64, true><<<NN, 256, 0, stream>>>(scores, xl, rowptr, csr_src, bias1, g1, be1, m1, v1, hbuf);

  // ---- layer 2: 256 -> 4x64 concat, BN+ELU ----
  lin_kernel<256, 256><<<NN, 256, 0, stream>>>(hbuf, Wl2, bl2, xl);
  lin_kernel<256, 256><<<NN, 256, 0, stream>>>(hbuf, Wr2, br2, xr);
  score_kernel<4, 64><<<(ETOT * 4 + 255) / 256, 256, 0, stream>>>(xl, xr, csr_src, csr_dst, att2, scores);
  agg_kernel<4, 64, true><<<NN, 256, 0, stream>>>(scores, xl, rowptr, csr_src, bias2, g2, be2, m2, v2, hbuf);

  // ---- layer 3: 256 -> 32, 1 head, mean(=identity) ----
  lin_kernel<256, 32><<<NN, 32, 0, stream>>>(hbuf, Wl3, bl3, xl);
  lin_kernel<256, 32><<<NN, 32, 0, stream>>>(hbuf, Wr3, br3, xr);
  score_kernel<1, 32><<<(ETOT + 255) / 256, 256, 0, stream>>>(xl, xr, csr_src, csr_dst, att3, scores);
  agg_kernel<1, 32, false><<<NN, 64, 0, stream>>>(scores, xl, rowptr, csr_src, bias3,
                                                  nullptr, nullptr, nullptr, nullptr, out);
}

// Round 2
// 645.004 us; speedup vs baseline: 3.3845x; 3.3845x over previous
//
#include <hip/hip_runtime.h>
#include <math.h>

#define NN 20000
#define EE 320000
#define ETOT (EE + NN)   // 340000 edges incl. self loops

// ---------------- CSR build ----------------
__global__ void deg_kernel(const int* __restrict__ ei, int* __restrict__ deg) {
  int e = blockIdx.x * 256 + threadIdx.x;
  if (e >= ETOT) return;
  int dst = (e < EE) ? ei[EE + e] : (e - EE);
  atomicAdd(&deg[dst], 1);
}

// single-block exclusive scan of deg[NN] -> rowptr[NN+1]
__global__ void scan_kernel(const int* __restrict__ deg, int* __restrict__ rowptr) {
  __shared__ int wsum[16];
  __shared__ int carry_s;
  const int tid = threadIdx.x;           // blockDim = 1024
  const int lane = tid & 63, wid = tid >> 6;
  if (tid == 0) carry_s = 0;
  __syncthreads();
  for (int base = 0; base < NN; base += 1024) {
    int i = base + tid;
    int v = (i < NN) ? deg[i] : 0;
    int x = v;
    #pragma unroll
    for (int off = 1; off < 64; off <<= 1) {
      int y = __shfl_up(x, off, 64);
      if (lane >= off) x += y;
    }
    if (lane == 63) wsum[wid] = x;
    __syncthreads();
    if (tid < 64) {
      int w = (tid < 16) ? wsum[tid] : 0;
      #pragma unroll
      for (int off = 1; off < 16; off <<= 1) {
        int y = __shfl_up(w, off, 64);
        if (lane >= off) w += y;
      }
      if (tid < 16) wsum[tid] = w;   // inclusive prefix of wave sums
    }
    __syncthreads();
    int incl = x + (wid > 0 ? wsum[wid - 1] : 0);
    int carry = carry_s;
    if (i < NN) rowptr[i] = carry + incl - v;   // exclusive
    __syncthreads();
    if (tid == 1023) carry_s = carry + incl;    // chunk total
    __syncthreads();
  }
  if (tid == 0) rowptr[NN] = carry_s;
}

__global__ void fill_kernel(const int* __restrict__ ei, int* __restrict__ cursor,
                            int* __restrict__ csr_src, int* __restrict__ csr_dst) {
  int e = blockIdx.x * 256 + threadIdx.x;
  if (e >= ETOT) return;
  int src, dst;
  if (e < EE) { src = ei[e]; dst = ei[EE + e]; } else { src = dst = e - EE; }
  int slot = atomicAdd(&cursor[dst], 1);
  csr_src[slot] = src;
  csr_dst[slot] = dst;
}

// ---------------- layer-1 linear (K=4): y[n][o] = b[o] + sum_i x[n][i]*W[o][i] ----------------
__global__ void lin1_kernel(const float* __restrict__ x, const float* __restrict__ W,
                            const float* __restrict__ b, float* __restrict__ y) {
  __shared__ float xs[4];
  int n = blockIdx.x;
  if (threadIdx.x < 4) xs[threadIdx.x] = x[(size_t)n * 4 + threadIdx.x];
  __syncthreads();
  int o = threadIdx.x;
  const float4 wv = *reinterpret_cast<const float4*>(W + (size_t)o * 4);
  float4 v = *reinterpret_cast<const float4*>(xs);
  y[(size_t)n * 256 + o] = wv.x * v.x + wv.y * v.y + wv.z * v.z + wv.w * v.w + b[o];
}

// ---------------- tiled fp32 GEMM: Y[M][N] = X[M][K] * W[N][K]^T + b ----------------
// TM=64, TK=32, 256 threads (16x16), micro-tile 4 x (TN/16) per thread.
template<int N, int TN>
__global__ __launch_bounds__(256) void gemm_kernel(
    const float* __restrict__ X, const float* __restrict__ W,
    const float* __restrict__ b, float* __restrict__ Y, int M) {
  constexpr int K = 256;
  constexpr int CN = TN / 16;
  __shared__ float Xs[32][68];        // [k][m], stride 272B (16B-aligned)
  __shared__ float Ws[32][TN + 4];    // [k][n]
  const int tid = threadIdx.x;
  const int ty = tid >> 4, tx = tid & 15;
  const int m0 = blockIdx.x * 64;
  const int n0 = blockIdx.y * TN;
  const int r = tid >> 3;             // 0..31
  const int c4 = (tid & 7) << 2;      // 0,4,...,28

  float acc[4][CN];
  #pragma unroll
  for (int i = 0; i < 4; ++i)
    #pragma unroll
    for (int j = 0; j < CN; ++j) acc[i][j] = 0.f;

  for (int k0 = 0; k0 < K; k0 += 32) {
    // stage X tile (64 x 32), transposed into Xs[k][m]
    #pragma unroll
    for (int rr = 0; rr < 64; rr += 32) {
      int m = m0 + r + rr;
      float4 v = make_float4(0.f, 0.f, 0.f, 0.f);
      if (m < M) v = *reinterpret_cast<const float4*>(&X[(size_t)m * K + k0 + c4]);
      Xs[c4 + 0][r + rr] = v.x; Xs[c4 + 1][r + rr] = v.y;
      Xs[c4 + 2][r + rr] = v.z; Xs[c4 + 3][r + rr] = v.w;
    }
    // stage W tile (TN x 32), transposed into Ws[k][n]
    #pragma unroll
    for (int rr = 0; rr < TN; rr += 32) {
      int n = n0 + r + rr;
      float4 v = *reinterpret_cast<const float4*>(&W[(size_t)n * K + k0 + c4]);
      Ws[c4 + 0][r + rr] = v.x; Ws[c4 + 1][r + rr] = v.y;
      Ws[c4 + 2][r + rr] = v.z; Ws[c4 + 3][r + rr] = v.w;
    }
    __syncthreads();
    #pragma unroll
    for (int kk = 0; kk < 32; ++kk) {
      float4 a = *reinterpret_cast<const float4*>(&Xs[kk][ty * 4]);
      float av[4] = {a.x, a.y, a.z, a.w};
      float bv[CN];
      #pragma unroll
      for (int j = 0; j < CN; ++j) bv[j] = Ws[kk][tx * CN + j];
      #pragma unroll
      for (int i = 0; i < 4; ++i)
        #pragma unroll
        for (int j = 0; j < CN; ++j) acc[i][j] = fmaf(av[i], bv[j], acc[i][j]);
    }
    __syncthreads();
  }
  #pragma unroll
  for (int i = 0; i < 4; ++i) {
    int m = m0 + ty * 4 + i;
    if (m < M) {
      #pragma unroll
      for (int j = 0; j < CN; ++j) {
        int n = n0 + tx * CN + j;
        Y[(size_t)m * N + n] = acc[i][j] + b[n];
      }
    }
  }
}

// ---------------- per-edge attention score ----------------
template<int H, int C>
__global__ void score_kernel(const float* __restrict__ xl, const float* __restrict__ xr,
                             const int* __restrict__ csr_src, const int* __restrict__ csr_dst,
                             const float* __restrict__ att, float* __restrict__ scores) {
  int id = blockIdx.x * 256 + threadIdx.x;
  if (id >= ETOT * H) return;
  int slot = id / H;
  int h = id - slot * H;
  int src = csr_src[slot], dst = csr_dst[slot];
  const float4* a = reinterpret_cast<const float4*>(xl + (size_t)src * (H * C) + h * C);
  const float4* bb = reinterpret_cast<const float4*>(xr + (size_t)dst * (H * C) + h * C);
  const float4* w = reinterpret_cast<const float4*>(att + h * C);
  float acc = 0.f;
  #pragma unroll
  for (int i = 0; i < C / 4; ++i) {
    float4 av = a[i], bv = bb[i], wv = w[i];
    float e0 = av.x + bv.x; e0 = (e0 > 0.f) ? e0 : 0.2f * e0;
    float e1 = av.y + bv.y; e1 = (e1 > 0.f) ? e1 : 0.2f * e1;
    float e2 = av.z + bv.z; e2 = (e2 > 0.f) ? e2 : 0.2f * e2;
    float e3 = av.w + bv.w; e3 = (e3 > 0.f) ? e3 : 0.2f * e3;
    acc += wv.x * e0 + wv.y * e1 + wv.z * e2 + wv.w * e3;
  }
  scores[slot * H + h] = acc;
}

// ---------------- per-node segment softmax + weighted aggregation (+bias, +BN+ELU) ----------------
template<int H, int C, bool BN_ELU>
__global__ void agg_kernel(const float* __restrict__ scores, const float* __restrict__ xl,
                           const int* __restrict__ rowptr, const int* __restrict__ csr_src,
                           const float* __restrict__ bias,
                           const float* __restrict__ bn_g, const float* __restrict__ bn_b,
                           const float* __restrict__ bn_m, const float* __restrict__ bn_v,
                           float* __restrict__ out) {
  const int F = H * C;
  int n = blockIdx.x;
  int h = threadIdx.x >> 6;
  int lane = threadIdx.x & 63;
  int beg = rowptr[n], end = rowptr[n + 1];
  float m = -3.4e38f;
  for (int s = beg + lane; s < end; s += 64) m = fmaxf(m, scores[s * H + h]);
  #pragma unroll
  for (int off = 32; off; off >>= 1) m = fmaxf(m, __shfl_xor(m, off, 64));
  float d = 0.f;
  for (int s = beg + lane; s < end; s += 64) d += expf(scores[s * H + h] - m);
  #pragma unroll
  for (int off = 32; off; off >>= 1) d += __shfl_xor(d, off, 64);
  d += 1e-16f;
  if (lane < C) {
    int c = lane;
    float acc = 0.f;
    for (int s = beg; s < end; ++s) {
      float w = expf(scores[s * H + h] - m);
      acc += w * xl[(size_t)csr_src[s] * F + h * C + c];
    }
    float v = acc / d + bias[h * C + c];
    if (BN_ELU) {
      int ch = h * C + c;
      float sc = bn_g[ch] * rsqrtf(bn_v[ch] + 1e-5f);
      v = sc * (v - bn_m[ch]) + bn_b[ch];
      v = (v > 0.f) ? v : expm1f(v);
    }
    out[(size_t)n * F + h * C + c] = v;
  }
}

extern "C" void kernel_launch(void* const* d_in, const int* in_sizes, int n_in,
                              void* d_out, int out_size, void* d_ws, size_t ws_size,
                              hipStream_t stream) {
  (void)in_sizes; (void)n_in; (void)out_size; (void)ws_size;
  const float* x  = (const float*)d_in[0];
  const int*   ei = (const int*)d_in[1];
  const float *Wl1 = (const float*)d_in[2],  *bl1 = (const float*)d_in[3],
              *Wr1 = (const float*)d_in[4],  *br1 = (const float*)d_in[5],
              *att1 = (const float*)d_in[6], *bias1 = (const float*)d_in[7],
              *g1 = (const float*)d_in[8],   *be1 = (const float*)d_in[9],
              *m1 = (const float*)d_in[10],  *v1 = (const float*)d_in[11];
  const float *Wl2 = (const float*)d_in[12], *bl2 = (const float*)d_in[13],
              *Wr2 = (const float*)d_in[14], *br2 = (const float*)d_in[15],
              *att2 = (const float*)d_in[16], *bias2 = (const float*)d_in[17],
              *g2 = (const float*)d_in[18],  *be2 = (const float*)d_in[19],
              *m2 = (const float*)d_in[20],  *v2 = (const float*)d_in[21];
  const float *Wl3 = (const float*)d_in[22], *bl3 = (const float*)d_in[23],
              *Wr3 = (const float*)d_in[24], *br3 = (const float*)d_in[25],
              *att3 = (const float*)d_in[26], *bias3 = (const float*)d_in[27];
  float* out = (float*)d_out;

  char* p = (char*)d_ws;
  auto alloc = [&](size_t bytes) { char* r = p; p += (bytes + 255) & ~(size_t)255; return r; };
  int*   deg     = (int*)alloc((size_t)NN * 4);
  int*   rowptr  = (int*)alloc((size_t)(NN + 1) * 4);
  int*   cursor  = (int*)alloc((size_t)NN * 4);
  int*   csr_src = (int*)alloc((size_t)ETOT * 4);
  int*   csr_dst = (int*)alloc((size_t)ETOT * 4);
  float* scores  = (float*)alloc((size_t)ETOT * 4 * 4);
  float* xl      = (float*)alloc((size_t)NN * 256 * 4);
  float* xr      = (float*)alloc((size_t)NN * 256 * 4);
  float* hbuf    = (float*)alloc((size_t)NN * 256 * 4);

  // CSR by dst
  hipMemsetAsync(deg, 0, (size_t)NN * 4, stream);
  deg_kernel<<<(ETOT + 255) / 256, 256, 0, stream>>>(ei, deg);
  scan_kernel<<<1, 1024, 0, stream>>>(deg, rowptr);
  hipMemcpyAsync(cursor, rowptr, (size_t)NN * 4, hipMemcpyDeviceToDevice, stream);
  fill_kernel<<<(ETOT + 255) / 256, 256, 0, stream>>>(ei, cursor, csr_src, csr_dst);

  dim3 g2d((NN + 63) / 64, 4);   // N=256, TN=64
  dim3 g3d((NN + 63) / 64, 1);   // N=32,  TN=32

  // ---- layer 1: 4 -> 4x64 concat, BN+ELU ----
  lin1_kernel<<<NN, 256, 0, stream>>>(x, Wl1, bl1, xl);
  lin1_kernel<<<NN, 256, 0, stream>>>(x, Wr1, br1, xr);
  score_kernel<4, 64><<<(ETOT * 4 + 255) / 256, 256, 0, stream>>>(xl, xr, csr_src, csr_dst, att1, scores);
  agg_kernel<4, 64, true><<<NN, 256, 0, stream>>>(scores, xl, rowptr, csr_src, bias1, g1, be1, m1, v1, hbuf);

  // ---- layer 2: 256 -> 4x64 concat, BN+ELU ----
  gemm_kernel<256, 64><<<g2d, 256, 0, stream>>>(hbuf, Wl2, bl2, xl, NN);
  gemm_kernel<256, 64><<<g2d, 256, 0, stream>>>(hbuf, Wr2, br2, xr, NN);
  score_kernel<4, 64><<<(ETOT * 4 + 255) / 256, 256, 0, stream>>>(xl, xr, csr_src, csr_dst, att2, scores);
  agg_kernel<4, 64, true><<<NN, 256, 0, stream>>>(scores, xl, rowptr, csr_src, bias2, g2, be2, m2, v2, hbuf);

  // ---- layer 3: 256 -> 32, 1 head, mean(=identity) ----
  gemm_kernel<32, 32><<<g3d, 256, 0, stream>>>(hbuf, Wl3, bl3, xl, NN);
  gemm_kernel<32, 32><<<g3d, 256, 0, stream>>>(hbuf, Wr3, br3, xr, NN);
  score_kernel<1, 32><<<(ETOT + 255) / 256, 256, 0, stream>>>(xl, xr, csr_src, csr_dst, att3, scores);
  agg_kernel<1, 32, false><<<NN, 64, 0, stream>>>(scores, xl, rowptr, csr_src, bias3,
                                                  nullptr, nullptr, nullptr, nullptr, out);
}

// Round 3
// 338.094 us; speedup vs baseline: 6.4568x; 1.9078x over previous
//
#include <hip/hip_runtime.h>
#include <math.h>

#define NN 20000
#define EE 320000
#define ETOT (EE + NN)   // 340000 edges incl. self loops

// ---------------- CSR build ----------------
__global__ void deg_kernel(const int* __restrict__ ei, int* __restrict__ deg) {
  int e = blockIdx.x * 256 + threadIdx.x;
  if (e >= ETOT) return;
  int dst = (e < EE) ? ei[EE + e] : (e - EE);
  atomicAdd(&deg[dst], 1);
}

// single-block exclusive scan of deg[NN] -> rowptr[NN+1]
__global__ void scan_kernel(const int* __restrict__ deg, int* __restrict__ rowptr) {
  __shared__ int wsum[16];
  __shared__ int carry_s;
  const int tid = threadIdx.x;           // blockDim = 1024
  const int lane = tid & 63, wid = tid >> 6;
  if (tid == 0) carry_s = 0;
  __syncthreads();
  for (int base = 0; base < NN; base += 1024) {
    int i = base + tid;
    int v = (i < NN) ? deg[i] : 0;
    int x = v;
    #pragma unroll
    for (int off = 1; off < 64; off <<= 1) {
      int y = __shfl_up(x, off, 64);
      if (lane >= off) x += y;
    }
    if (lane == 63) wsum[wid] = x;
    __syncthreads();
    if (tid < 64) {
      int w = (tid < 16) ? wsum[tid] : 0;
      #pragma unroll
      for (int off = 1; off < 16; off <<= 1) {
        int y = __shfl_up(w, off, 64);
        if (lane >= off) w += y;
      }
      if (tid < 16) wsum[tid] = w;   // inclusive prefix of wave sums
    }
    __syncthreads();
    int incl = x + (wid > 0 ? wsum[wid - 1] : 0);
    int carry = carry_s;
    if (i < NN) rowptr[i] = carry + incl - v;   // exclusive
    __syncthreads();
    if (tid == 1023) carry_s = carry + incl;    // chunk total
    __syncthreads();
  }
  if (tid == 0) rowptr[NN] = carry_s;
}

__global__ void fill_kernel(const int* __restrict__ ei, int* __restrict__ cursor,
                            int* __restrict__ csr_src) {
  int e = blockIdx.x * 256 + threadIdx.x;
  if (e >= ETOT) return;
  int src, dst;
  if (e < EE) { src = ei[e]; dst = ei[EE + e]; } else { src = dst = e - EE; }
  int slot = atomicAdd(&cursor[dst], 1);
  csr_src[slot] = src;
}

// ---------------- layer-1 linear (K=4) ----------------
__global__ void lin1_kernel(const float* __restrict__ x, const float* __restrict__ W,
                            const float* __restrict__ b, float* __restrict__ y) {
  __shared__ float xs[4];
  int n = blockIdx.x;
  if (threadIdx.x < 4) xs[threadIdx.x] = x[(size_t)n * 4 + threadIdx.x];
  __syncthreads();
  int o = threadIdx.x;
  const float4 wv = *reinterpret_cast<const float4*>(W + (size_t)o * 4);
  float4 v = *reinterpret_cast<const float4*>(xs);
  y[(size_t)n * 256 + o] = wv.x * v.x + wv.y * v.y + wv.z * v.z + wv.w * v.w + b[o];
}

// ---------------- tiled fp32 GEMM: Y[M][N] = X[M][K] * W[N][K]^T + b ----------------
template<int N, int TN>
__global__ __launch_bounds__(256) void gemm_kernel(
    const float* __restrict__ X, const float* __restrict__ W,
    const float* __restrict__ b, float* __restrict__ Y, int M) {
  constexpr int K = 256;
  constexpr int CN = TN / 16;
  __shared__ float Xs[32][68];
  __shared__ float Ws[32][TN + 4];
  const int tid = threadIdx.x;
  const int ty = tid >> 4, tx = tid & 15;
  const int m0 = blockIdx.x * 64;
  const int n0 = blockIdx.y * TN;
  const int r = tid >> 3;
  const int c4 = (tid & 7) << 2;

  float acc[4][CN];
  #pragma unroll
  for (int i = 0; i < 4; ++i)
    #pragma unroll
    for (int j = 0; j < CN; ++j) acc[i][j] = 0.f;

  for (int k0 = 0; k0 < K; k0 += 32) {
    #pragma unroll
    for (int rr = 0; rr < 64; rr += 32) {
      int m = m0 + r + rr;
      float4 v = make_float4(0.f, 0.f, 0.f, 0.f);
      if (m < M) v = *reinterpret_cast<const float4*>(&X[(size_t)m * K + k0 + c4]);
      Xs[c4 + 0][r + rr] = v.x; Xs[c4 + 1][r + rr] = v.y;
      Xs[c4 + 2][r + rr] = v.z; Xs[c4 + 3][r + rr] = v.w;
    }
    #pragma unroll
    for (int rr = 0; rr < TN; rr += 32) {
      int n = n0 + r + rr;
      float4 v = *reinterpret_cast<const float4*>(&W[(size_t)n * K + k0 + c4]);
      Ws[c4 + 0][r + rr] = v.x; Ws[c4 + 1][r + rr] = v.y;
      Ws[c4 + 2][r + rr] = v.z; Ws[c4 + 3][r + rr] = v.w;
    }
    __syncthreads();
    #pragma unroll
    for (int kk = 0; kk < 32; ++kk) {
      float4 a = *reinterpret_cast<const float4*>(&Xs[kk][ty * 4]);
      float av[4] = {a.x, a.y, a.z, a.w};
      float bv[CN];
      #pragma unroll
      for (int j = 0; j < CN; ++j) bv[j] = Ws[kk][tx * CN + j];
      #pragma unroll
      for (int i = 0; i < 4; ++i)
        #pragma unroll
        for (int j = 0; j < CN; ++j) acc[i][j] = fmaf(av[i], bv[j], acc[i][j]);
    }
    __syncthreads();
  }
  #pragma unroll
  for (int i = 0; i < 4; ++i) {
    int m = m0 + ty * 4 + i;
    if (m < M) {
      #pragma unroll
      for (int j = 0; j < CN; ++j) {
        int n = n0 + tx * CN + j;
        Y[(size_t)m * N + n] = acc[i][j] + b[n];
      }
    }
  }
}

// ---------------- fused GATv2 attention + aggregation, H=4, C=64 ----------------
// 4 nodes per block; one wave per node; lane owns 4 channels (float4).
// Head g = lane>>4 (16 lanes per head). Online softmax in registers.
template<bool BN_ELU>
__global__ __launch_bounds__(256) void fused_agg4(
    const float* __restrict__ xl, const float* __restrict__ xr,
    const int* __restrict__ rowptr, const int* __restrict__ csr_src,
    const float* __restrict__ att, const float* __restrict__ bias,
    const float* __restrict__ bn_g, const float* __restrict__ bn_b,
    const float* __restrict__ bn_m, const float* __restrict__ bn_v,
    float* __restrict__ out) {
  int n = blockIdx.x * 4 + (threadIdx.x >> 6);
  if (n >= NN) return;
  int lane = threadIdx.x & 63;
  float4 xrv = reinterpret_cast<const float4*>(xr + (size_t)n * 256)[lane];
  float4 atv = reinterpret_cast<const float4*>(att)[lane];
  int beg = rowptr[n], end = rowptr[n + 1];
  float m = -3.4e38f, d = 0.f;
  float a0 = 0.f, a1 = 0.f, a2 = 0.f, a3 = 0.f;
  for (int s = beg; s < end; ++s) {
    int src = csr_src[s];
    float4 xlv = reinterpret_cast<const float4*>(xl + (size_t)src * 256)[lane];
    float e0 = xlv.x + xrv.x; e0 = (e0 > 0.f) ? e0 : 0.2f * e0;
    float e1 = xlv.y + xrv.y; e1 = (e1 > 0.f) ? e1 : 0.2f * e1;
    float e2 = xlv.z + xrv.z; e2 = (e2 > 0.f) ? e2 : 0.2f * e2;
    float e3 = xlv.w + xrv.w; e3 = (e3 > 0.f) ? e3 : 0.2f * e3;
    float sc = atv.x * e0 + atv.y * e1 + atv.z * e2 + atv.w * e3;
    #pragma unroll
    for (int off = 8; off; off >>= 1) sc += __shfl_xor(sc, off, 64);  // per-head (16-lane) sum
    float mn = fmaxf(m, sc);
    float scale = __expf(m - mn);
    float w = __expf(sc - mn);
    a0 = a0 * scale + w * xlv.x;
    a1 = a1 * scale + w * xlv.y;
    a2 = a2 * scale + w * xlv.z;
    a3 = a3 * scale + w * xlv.w;
    d = d * scale + w;
    m = mn;
  }
  float inv = 1.f / (d + 1e-16f);
  float4 bsv = reinterpret_cast<const float4*>(bias)[lane];
  float v0 = a0 * inv + bsv.x, v1 = a1 * inv + bsv.y;
  float v2 = a2 * inv + bsv.z, v3 = a3 * inv + bsv.w;
  if (BN_ELU) {
    float4 g = reinterpret_cast<const float4*>(bn_g)[lane];
    float4 bb = reinterpret_cast<const float4*>(bn_b)[lane];
    float4 mu = reinterpret_cast<const float4*>(bn_m)[lane];
    float4 va = reinterpret_cast<const float4*>(bn_v)[lane];
    float s0 = g.x * rsqrtf(va.x + 1e-5f), s1 = g.y * rsqrtf(va.y + 1e-5f);
    float s2 = g.z * rsqrtf(va.z + 1e-5f), s3 = g.w * rsqrtf(va.w + 1e-5f);
    v0 = s0 * (v0 - mu.x) + bb.x; v0 = (v0 > 0.f) ? v0 : expm1f(v0);
    v1 = s1 * (v1 - mu.y) + bb.y; v1 = (v1 > 0.f) ? v1 : expm1f(v1);
    v2 = s2 * (v2 - mu.z) + bb.z; v2 = (v2 > 0.f) ? v2 : expm1f(v2);
    v3 = s3 * (v3 - mu.w) + bb.w; v3 = (v3 > 0.f) ? v3 : expm1f(v3);
  }
  reinterpret_cast<float4*>(out + (size_t)n * 256)[lane] =
      make_float4(v0, v1, v2, v3);
}

// ---------------- fused layer 3: H=1, C=32, bias only ----------------
// 4 nodes per block; wave per node; 16 lanes per edge (float2/lane), 4 edges in flight.
__global__ __launch_bounds__(256) void fused_agg3(
    const float* __restrict__ xl, const float* __restrict__ xr,
    const int* __restrict__ rowptr, const int* __restrict__ csr_src,
    const float* __restrict__ att, const float* __restrict__ bias,
    float* __restrict__ out) {
  int n = blockIdx.x * 4 + (threadIdx.x >> 6);
  if (n >= NN) return;
  int lane = threadIdx.x & 63;
  int grp = lane >> 4;        // which of 4 edges in flight
  int cl = lane & 15;         // channel pair index
  float2 xrv = reinterpret_cast<const float2*>(xr + (size_t)n * 32)[cl];
  float2 atv = reinterpret_cast<const float2*>(att)[cl];
  int beg = rowptr[n], end = rowptr[n + 1];
  float m = -3.4e38f, d = 0.f, a0 = 0.f, a1 = 0.f;
  for (int s = beg + grp; s < end; s += 4) {
    int src = csr_src[s];
    float2 xlv = reinterpret_cast<const float2*>(xl + (size_t)src * 32)[cl];
    float e0 = xlv.x + xrv.x; e0 = (e0 > 0.f) ? e0 : 0.2f * e0;
    float e1 = xlv.y + xrv.y; e1 = (e1 > 0.f) ? e1 : 0.2f * e1;
    float sc = atv.x * e0 + atv.y * e1;
    #pragma unroll
    for (int off = 8; off; off >>= 1) sc += __shfl_xor(sc, off, 64);  // 16-lane sum
    float mn = fmaxf(m, sc);
    float scale = __expf(m - mn);
    float w = __expf(sc - mn);
    a0 = a0 * scale + w * xlv.x;
    a1 = a1 * scale + w * xlv.y;
    d = d * scale + w;
    m = mn;
  }
  // merge the 4 per-group online states (tree over lane^16, lane^32)
  #pragma unroll
  for (int off = 16; off <= 32; off <<= 1) {
    float mo = __shfl_xor(m, off, 64);
    float doo = __shfl_xor(d, off, 64);
    float b0 = __shfl_xor(a0, off, 64);
    float b1 = __shfl_xor(a1, off, 64);
    float mn = fmaxf(m, mo);
    float se = __expf(m - mn), so = __expf(mo - mn);
    a0 = a0 * se + b0 * so;
    a1 = a1 * se + b1 * so;
    d = d * se + doo * so;
    m = mn;
  }
  if (grp == 0) {
    float inv = 1.f / (d + 1e-16f);
    float2 bsv = reinterpret_cast<const float2*>(bias)[cl];
    reinterpret_cast<float2*>(out + (size_t)n * 32)[cl] =
        make_float2(a0 * inv + bsv.x, a1 * inv + bsv.y);
  }
}

extern "C" void kernel_launch(void* const* d_in, const int* in_sizes, int n_in,
                              void* d_out, int out_size, void* d_ws, size_t ws_size,
                              hipStream_t stream) {
  (void)in_sizes; (void)n_in; (void)out_size; (void)ws_size;
  const float* x  = (const float*)d_in[0];
  const int*   ei = (const int*)d_in[1];
  const float *Wl1 = (const float*)d_in[2],  *bl1 = (const float*)d_in[3],
              *Wr1 = (const float*)d_in[4],  *br1 = (const float*)d_in[5],
              *att1 = (const float*)d_in[6], *bias1 = (const float*)d_in[7],
              *g1 = (const float*)d_in[8],   *be1 = (const float*)d_in[9],
              *m1 = (const float*)d_in[10],  *v1 = (const float*)d_in[11];
  const float *Wl2 = (const float*)d_in[12], *bl2 = (const float*)d_in[13],
              *Wr2 = (const float*)d_in[14], *br2 = (const float*)d_in[15],
              *att2 = (const float*)d_in[16], *bias2 = (const float*)d_in[17],
              *g2 = (const float*)d_in[18],  *be2 = (const float*)d_in[19],
              *m2 = (const float*)d_in[20],  *v2 = (const float*)d_in[21];
  const float *Wl3 = (const float*)d_in[22], *bl3 = (const float*)d_in[23],
              *Wr3 = (const float*)d_in[24], *br3 = (const float*)d_in[25],
              *att3 = (const float*)d_in[26], *bias3 = (const float*)d_in[27];
  float* out = (float*)d_out;

  char* p = (char*)d_ws;
  auto alloc = [&](size_t bytes) { char* r = p; p += (bytes + 255) & ~(size_t)255; return r; };
  int*   deg     = (int*)alloc((size_t)NN * 4);
  int*   rowptr  = (int*)alloc((size_t)(NN + 1) * 4);
  int*   cursor  = (int*)alloc((size_t)NN * 4);
  int*   csr_src = (int*)alloc((size_t)ETOT * 4);
  float* xl      = (float*)alloc((size_t)NN * 256 * 4);
  float* xr      = (float*)alloc((size_t)NN * 256 * 4);
  float* hbuf    = (float*)alloc((size_t)NN * 256 * 4);

  // CSR by dst
  hipMemsetAsync(deg, 0, (size_t)NN * 4, stream);
  deg_kernel<<<(ETOT + 255) / 256, 256, 0, stream>>>(ei, deg);
  scan_kernel<<<1, 1024, 0, stream>>>(deg, rowptr);
  hipMemcpyAsync(cursor, rowptr, (size_t)NN * 4, hipMemcpyDeviceToDevice, stream);
  fill_kernel<<<(ETOT + 255) / 256, 256, 0, stream>>>(ei, cursor, csr_src);

  dim3 g2d((NN + 63) / 64, 4);   // N=256, TN=64
  dim3 g3d((NN + 63) / 64, 1);   // N=32,  TN=32
  int nb = (NN + 3) / 4;

  // ---- layer 1: 4 -> 4x64 concat, BN+ELU ----
  lin1_kernel<<<NN, 256, 0, stream>>>(x, Wl1, bl1, xl);
  lin1_kernel<<<NN, 256, 0, stream>>>(x, Wr1, br1, xr);
  fused_agg4<true><<<nb, 256, 0, stream>>>(xl, xr, rowptr, csr_src, att1, bias1,
                                           g1, be1, m1, v1, hbuf);

  // ---- layer 2: 256 -> 4x64 concat, BN+ELU ----
  gemm_kernel<256, 64><<<g2d, 256, 0, stream>>>(hbuf, Wl2, bl2, xl, NN);
  gemm_kernel<256, 64><<<g2d, 256, 0, stream>>>(hbuf, Wr2, br2, xr, NN);
  fused_agg4<true><<<nb, 256, 0, stream>>>(xl, xr, rowptr, csr_src, att2, bias2,
                                           g2, be2, m2, v2, hbuf);

  // ---- layer 3: 256 -> 32, 1 head, mean(=identity) ----
  gemm_kernel<32, 32><<<g3d, 256, 0, stream>>>(hbuf, Wl3, bl3, xl, NN);
  gemm_kernel<32, 32><<<g3d, 256, 0, stream>>>(hbuf, Wr3, br3, xr, NN);
  fused_agg3<<<nb, 256, 0, stream>>>(xl, xr, rowptr, csr_src, att3, bias3, out);
}

// Round 4
// 332.025 us; speedup vs baseline: 6.5748x; 1.0183x over previous
//
#include <hip/hip_runtime.h>
#include <math.h>

#define NN 20000
#define EE 320000
#define ETOT (EE + NN)   // 340000 edges incl. self loops

typedef unsigned short ushort_t;
typedef unsigned int uint_t;

__device__ __forceinline__ ushort_t f2bf(float f) {
  union { float f; uint_t u; } v; v.f = f;
  uint_t r = v.u + 0x7FFF + ((v.u >> 16) & 1);   // RNE
  return (ushort_t)(r >> 16);
}
__device__ __forceinline__ float bf2f(uint_t hi16) {
  union { uint_t u; float f; } v; v.u = hi16 << 16;
  return v.f;
}

// ---------------- CSR build ----------------
__global__ void deg_kernel(const int* __restrict__ ei, int* __restrict__ deg) {
  int e = blockIdx.x * 256 + threadIdx.x;
  if (e >= ETOT) return;
  int dst = (e < EE) ? ei[EE + e] : (e - EE);
  atomicAdd(&deg[dst], 1);
}

// single-block exclusive scan of deg[NN] -> rowptr[NN+1]
__global__ void scan_kernel(const int* __restrict__ deg, int* __restrict__ rowptr) {
  __shared__ int wsum[16];
  __shared__ int carry_s;
  const int tid = threadIdx.x;           // blockDim = 1024
  const int lane = tid & 63, wid = tid >> 6;
  if (tid == 0) carry_s = 0;
  __syncthreads();
  for (int base = 0; base < NN; base += 1024) {
    int i = base + tid;
    int v = (i < NN) ? deg[i] : 0;
    int x = v;
    #pragma unroll
    for (int off = 1; off < 64; off <<= 1) {
      int y = __shfl_up(x, off, 64);
      if (lane >= off) x += y;
    }
    if (lane == 63) wsum[wid] = x;
    __syncthreads();
    if (tid < 64) {
      int w = (tid < 16) ? wsum[tid] : 0;
      #pragma unroll
      for (int off = 1; off < 16; off <<= 1) {
        int y = __shfl_up(w, off, 64);
        if (lane >= off) w += y;
      }
      if (tid < 16) wsum[tid] = w;   // inclusive prefix of wave sums
    }
    __syncthreads();
    int incl = x + (wid > 0 ? wsum[wid - 1] : 0);
    int carry = carry_s;
    if (i < NN) rowptr[i] = carry + incl - v;   // exclusive
    __syncthreads();
    if (tid == 1023) carry_s = carry + incl;    // chunk total
    __syncthreads();
  }
  if (tid == 0) rowptr[NN] = carry_s;
}

__global__ void fill_kernel(const int* __restrict__ ei, int* __restrict__ cursor,
                            int* __restrict__ csr_src) {
  int e = blockIdx.x * 256 + threadIdx.x;
  if (e >= ETOT) return;
  int src, dst;
  if (e < EE) { src = ei[e]; dst = ei[EE + e]; } else { src = dst = e - EE; }
  int slot = atomicAdd(&cursor[dst], 1);
  csr_src[slot] = src;
}

// ---------------- layer-1 linear (K=4), bf16 output ----------------
__global__ void lin1_kernel(const float* __restrict__ x, const float* __restrict__ W,
                            const float* __restrict__ b, ushort_t* __restrict__ y) {
  __shared__ float xs[4];
  int n = blockIdx.x;
  if (threadIdx.x < 4) xs[threadIdx.x] = x[(size_t)n * 4 + threadIdx.x];
  __syncthreads();
  int o = threadIdx.x;
  const float4 wv = *reinterpret_cast<const float4*>(W + (size_t)o * 4);
  float4 v = *reinterpret_cast<const float4*>(xs);
  y[(size_t)n * 256 + o] = f2bf(wv.x * v.x + wv.y * v.y + wv.z * v.z + wv.w * v.w + b[o]);
}

// ---------------- tiled fp32 GEMM: Y[M][N] = X[M][K] * W[N][K]^T + b, bf16 output ----------------
template<int N, int TN>
__global__ __launch_bounds__(256) void gemm_kernel(
    const float* __restrict__ X, const float* __restrict__ W,
    const float* __restrict__ b, ushort_t* __restrict__ Y, int M) {
  constexpr int K = 256;
  constexpr int CN = TN / 16;
  __shared__ float Xs[32][68];
  __shared__ float Ws[32][TN + 4];
  const int tid = threadIdx.x;
  const int ty = tid >> 4, tx = tid & 15;
  const int m0 = blockIdx.x * 64;
  const int n0 = blockIdx.y * TN;
  const int r = tid >> 3;
  const int c4 = (tid & 7) << 2;

  float acc[4][CN];
  #pragma unroll
  for (int i = 0; i < 4; ++i)
    #pragma unroll
    for (int j = 0; j < CN; ++j) acc[i][j] = 0.f;

  for (int k0 = 0; k0 < K; k0 += 32) {
    #pragma unroll
    for (int rr = 0; rr < 64; rr += 32) {
      int m = m0 + r + rr;
      float4 v = make_float4(0.f, 0.f, 0.f, 0.f);
      if (m < M) v = *reinterpret_cast<const float4*>(&X[(size_t)m * K + k0 + c4]);
      Xs[c4 + 0][r + rr] = v.x; Xs[c4 + 1][r + rr] = v.y;
      Xs[c4 + 2][r + rr] = v.z; Xs[c4 + 3][r + rr] = v.w;
    }
    #pragma unroll
    for (int rr = 0; rr < TN; rr += 32) {
      int n = n0 + r + rr;
      float4 v = *reinterpret_cast<const float4*>(&W[(size_t)n * K + k0 + c4]);
      Ws[c4 + 0][r + rr] = v.x; Ws[c4 + 1][r + rr] = v.y;
      Ws[c4 + 2][r + rr] = v.z; Ws[c4 + 3][r + rr] = v.w;
    }
    __syncthreads();
    #pragma unroll
    for (int kk = 0; kk < 32; ++kk) {
      float4 a = *reinterpret_cast<const float4*>(&Xs[kk][ty * 4]);
      float av[4] = {a.x, a.y, a.z, a.w};
      float bv[CN];
      #pragma unroll
      for (int j = 0; j < CN; ++j) bv[j] = Ws[kk][tx * CN + j];
      #pragma unroll
      for (int i = 0; i < 4; ++i)
        #pragma unroll
        for (int j = 0; j < CN; ++j) acc[i][j] = fmaf(av[i], bv[j], acc[i][j]);
    }
    __syncthreads();
  }
  #pragma unroll
  for (int i = 0; i < 4; ++i) {
    int m = m0 + ty * 4 + i;
    if (m < M) {
      #pragma unroll
      for (int j = 0; j < CN; ++j) {
        int n = n0 + tx * CN + j;
        Y[(size_t)m * N + n] = f2bf(acc[i][j] + b[n]);
      }
    }
  }
}

// ---------------- fused GATv2 attention + aggregation, H=4, C=64, bf16 inputs ----------------
// 4 nodes per block; one wave per node; lane owns 4 channels (uint2 = 4 bf16).
template<bool BN_ELU>
__global__ __launch_bounds__(256) void fused_agg4(
    const ushort_t* __restrict__ xl, const ushort_t* __restrict__ xr,
    const int* __restrict__ rowptr, const int* __restrict__ csr_src,
    const float* __restrict__ att, const float* __restrict__ bias,
    const float* __restrict__ bn_g, const float* __restrict__ bn_b,
    const float* __restrict__ bn_m, const float* __restrict__ bn_v,
    float* __restrict__ out) {
  int n = blockIdx.x * 4 + (threadIdx.x >> 6);
  if (n >= NN) return;
  int lane = threadIdx.x & 63;
  uint2 xru = reinterpret_cast<const uint2*>(xr + (size_t)n * 256)[lane];
  float xr0 = bf2f(xru.x & 0xFFFF), xr1 = bf2f(xru.x >> 16);
  float xr2 = bf2f(xru.y & 0xFFFF), xr3 = bf2f(xru.y >> 16);
  float4 atv = reinterpret_cast<const float4*>(att)[lane];
  int beg = rowptr[n], end = rowptr[n + 1];
  float m = -3.4e38f, d = 0.f;
  float a0 = 0.f, a1 = 0.f, a2 = 0.f, a3 = 0.f;
  for (int s = beg; s < end; ++s) {
    int src = csr_src[s];
    uint2 xu = reinterpret_cast<const uint2*>(xl + (size_t)src * 256)[lane];
    float x0 = bf2f(xu.x & 0xFFFF), x1 = bf2f(xu.x >> 16);
    float x2 = bf2f(xu.y & 0xFFFF), x3 = bf2f(xu.y >> 16);
    float e0 = x0 + xr0; e0 = (e0 > 0.f) ? e0 : 0.2f * e0;
    float e1 = x1 + xr1; e1 = (e1 > 0.f) ? e1 : 0.2f * e1;
    float e2 = x2 + xr2; e2 = (e2 > 0.f) ? e2 : 0.2f * e2;
    float e3 = x3 + xr3; e3 = (e3 > 0.f) ? e3 : 0.2f * e3;
    float sc = atv.x * e0 + atv.y * e1 + atv.z * e2 + atv.w * e3;
    #pragma unroll
    for (int off = 8; off; off >>= 1) sc += __shfl_xor(sc, off, 64);  // per-head (16-lane) sum
    float mn = fmaxf(m, sc);
    float scale = __expf(m - mn);
    float w = __expf(sc - mn);
    a0 = a0 * scale + w * x0;
    a1 = a1 * scale + w * x1;
    a2 = a2 * scale + w * x2;
    a3 = a3 * scale + w * x3;
    d = d * scale + w;
    m = mn;
  }
  float inv = 1.f / (d + 1e-16f);
  float4 bsv = reinterpret_cast<const float4*>(bias)[lane];
  float v0 = a0 * inv + bsv.x, v1 = a1 * inv + bsv.y;
  float v2 = a2 * inv + bsv.z, v3 = a3 * inv + bsv.w;
  if (BN_ELU) {
    float4 g = reinterpret_cast<const float4*>(bn_g)[lane];
    float4 bb = reinterpret_cast<const float4*>(bn_b)[lane];
    float4 mu = reinterpret_cast<const float4*>(bn_m)[lane];
    float4 va = reinterpret_cast<const float4*>(bn_v)[lane];
    float s0 = g.x * rsqrtf(va.x + 1e-5f), s1 = g.y * rsqrtf(va.y + 1e-5f);
    float s2 = g.z * rsqrtf(va.z + 1e-5f), s3 = g.w * rsqrtf(va.w + 1e-5f);
    v0 = s0 * (v0 - mu.x) + bb.x; v0 = (v0 > 0.f) ? v0 : expm1f(v0);
    v1 = s1 * (v1 - mu.y) + bb.y; v1 = (v1 > 0.f) ? v1 : expm1f(v1);
    v2 = s2 * (v2 - mu.z) + bb.z; v2 = (v2 > 0.f) ? v2 : expm1f(v2);
    v3 = s3 * (v3 - mu.w) + bb.w; v3 = (v3 > 0.f) ? v3 : expm1f(v3);
  }
  reinterpret_cast<float4*>(out + (size_t)n * 256)[lane] =
      make_float4(v0, v1, v2, v3);
}

// ---------------- fused layer 3: H=1, C=32, bias only, bf16 inputs ----------------
// 4 nodes per block; wave per node; 16 lanes per edge (2 ch/lane), 4 edges in flight.
__global__ __launch_bounds__(256) void fused_agg3(
    const ushort_t* __restrict__ xl, const ushort_t* __restrict__ xr,
    const int* __restrict__ rowptr, const int* __restrict__ csr_src,
    const float* __restrict__ att, const float* __restrict__ bias,
    float* __restrict__ out) {
  int n = blockIdx.x * 4 + (threadIdx.x >> 6);
  if (n >= NN) return;
  int lane = threadIdx.x & 63;
  int grp = lane >> 4;        // which of 4 edges in flight
  int cl = lane & 15;         // channel pair index
  uint_t xru = reinterpret_cast<const uint_t*>(xr + (size_t)n * 32)[cl];
  float xr0 = bf2f(xru & 0xFFFF), xr1 = bf2f(xru >> 16);
  float2 atv = reinterpret_cast<const float2*>(att)[cl];
  int beg = rowptr[n], end = rowptr[n + 1];
  float m = -3.4e38f, d = 0.f, a0 = 0.f, a1 = 0.f;
  for (int s = beg + grp; s < end; s += 4) {
    int src = csr_src[s];
    uint_t xu = reinterpret_cast<const uint_t*>(xl + (size_t)src * 32)[cl];
    float x0 = bf2f(xu & 0xFFFF), x1 = bf2f(xu >> 16);
    float e0 = x0 + xr0; e0 = (e0 > 0.f) ? e0 : 0.2f * e0;
    float e1 = x1 + xr1; e1 = (e1 > 0.f) ? e1 : 0.2f * e1;
    float sc = atv.x * e0 + atv.y * e1;
    #pragma unroll
    for (int off = 8; off; off >>= 1) sc += __shfl_xor(sc, off, 64);  // 16-lane sum
    float mn = fmaxf(m, sc);
    float scale = __expf(m - mn);
    float w = __expf(sc - mn);
    a0 = a0 * scale + w * x0;
    a1 = a1 * scale + w * x1;
    d = d * scale + w;
    m = mn;
  }
  // merge the 4 per-group online states
  #pragma unroll
  for (int off = 16; off <= 32; off <<= 1) {
    float mo = __shfl_xor(m, off, 64);
    float doo = __shfl_xor(d, off, 64);
    float b0 = __shfl_xor(a0, off, 64);
    float b1 = __shfl_xor(a1, off, 64);
    float mn = fmaxf(m, mo);
    float se = __expf(m - mn), so = __expf(mo - mn);
    a0 = a0 * se + b0 * so;
    a1 = a1 * se + b1 * so;
    d = d * se + doo * so;
    m = mn;
  }
  if (grp == 0) {
    float inv = 1.f / (d + 1e-16f);
    float2 bsv = reinterpret_cast<const float2*>(bias)[cl];
    reinterpret_cast<float2*>(out + (size_t)n * 32)[cl] =
        make_float2(a0 * inv + bsv.x, a1 * inv + bsv.y);
  }
}

extern "C" void kernel_launch(void* const* d_in, const int* in_sizes, int n_in,
                              void* d_out, int out_size, void* d_ws, size_t ws_size,
                              hipStream_t stream) {
  (void)in_sizes; (void)n_in; (void)out_size; (void)ws_size;
  const float* x  = (const float*)d_in[0];
  const int*   ei = (const int*)d_in[1];
  const float *Wl1 = (const float*)d_in[2],  *bl1 = (const float*)d_in[3],
              *Wr1 = (const float*)d_in[4],  *br1 = (const float*)d_in[5],
              *att1 = (const float*)d_in[6], *bias1 = (const float*)d_in[7],
              *g1 = (const float*)d_in[8],   *be1 = (const float*)d_in[9],
              *m1 = (const float*)d_in[10],  *v1 = (const float*)d_in[11];
  const float *Wl2 = (const float*)d_in[12], *bl2 = (const float*)d_in[13],
              *Wr2 = (const float*)d_in[14], *br2 = (const float*)d_in[15],
              *att2 = (const float*)d_in[16], *bias2 = (const float*)d_in[17],
              *g2 = (const float*)d_in[18],  *be2 = (const float*)d_in[19],
              *m2 = (const float*)d_in[20],  *v2 = (const float*)d_in[21];
  const float *Wl3 = (const float*)d_in[22], *bl3 = (const float*)d_in[23],
              *Wr3 = (const float*)d_in[24], *br3 = (const float*)d_in[25],
              *att3 = (const float*)d_in[26], *bias3 = (const float*)d_in[27];
  float* out = (float*)d_out;

  char* p = (char*)d_ws;
  auto alloc = [&](size_t bytes) { char* r = p; p += (bytes + 255) & ~(size_t)255; return r; };
  int*      deg     = (int*)alloc((size_t)NN * 4);
  int*      rowptr  = (int*)alloc((size_t)(NN + 1) * 4);
  int*      cursor  = (int*)alloc((size_t)NN * 4);
  int*      csr_src = (int*)alloc((size_t)ETOT * 4);
  ushort_t* xl      = (ushort_t*)alloc((size_t)NN * 256 * 2);
  ushort_t* xr      = (ushort_t*)alloc((size_t)NN * 256 * 2);
  float*    hbuf    = (float*)alloc((size_t)NN * 256 * 4);

  // CSR by dst
  hipMemsetAsync(deg, 0, (size_t)NN * 4, stream);
  deg_kernel<<<(ETOT + 255) / 256, 256, 0, stream>>>(ei, deg);
  scan_kernel<<<1, 1024, 0, stream>>>(deg, rowptr);
  hipMemcpyAsync(cursor, rowptr, (size_t)NN * 4, hipMemcpyDeviceToDevice, stream);
  fill_kernel<<<(ETOT + 255) / 256, 256, 0, stream>>>(ei, cursor, csr_src);

  dim3 g2d((NN + 63) / 64, 4);   // N=256, TN=64
  dim3 g3d((NN + 63) / 64, 1);   // N=32,  TN=32
  int nb = (NN + 3) / 4;

  // ---- layer 1: 4 -> 4x64 concat, BN+ELU ----
  lin1_kernel<<<NN, 256, 0, stream>>>(x, Wl1, bl1, xl);
  lin1_kernel<<<NN, 256, 0, stream>>>(x, Wr1, br1, xr);
  fused_agg4<true><<<nb, 256, 0, stream>>>(xl, xr, rowptr, csr_src, att1, bias1,
                                           g1, be1, m1, v1, hbuf);

  // ---- layer 2: 256 -> 4x64 concat, BN+ELU ----
  gemm_kernel<256, 64><<<g2d, 256, 0, stream>>>(hbuf, Wl2, bl2, xl, NN);
  gemm_kernel<256, 64><<<g2d, 256, 0, stream>>>(hbuf, Wr2, br2, xr, NN);
  fused_agg4<true><<<nb, 256, 0, stream>>>(xl, xr, rowptr, csr_src, att2, bias2,
                                           g2, be2, m2, v2, hbuf);

  // ---- layer 3: 256 -> 32, 1 head, mean(=identity) ----
  gemm_kernel<32, 32><<<g3d, 256, 0, stream>>>(hbuf, Wl3, bl3, xl, NN);
  gemm_kernel<32, 32><<<g3d, 256, 0, stream>>>(hbuf, Wr3, br3, xr, NN);
  fused_agg3<<<nb, 256, 0, stream>>>(xl, xr, rowptr, csr_src, att3, bias3, out);
}

// Round 5
// 278.198 us; speedup vs baseline: 7.8470x; 1.1935x over previous
//
#include <hip/hip_runtime.h>
#include <math.h>

#define NN 20000
#define EE 320000
#define ETOT (EE + NN)   // 340000 edges incl. self loops

typedef unsigned short ushort_t;
typedef unsigned int uint_t;
typedef __attribute__((ext_vector_type(8))) short bf16x8;
typedef __attribute__((ext_vector_type(4))) float f32x4;

__device__ __forceinline__ ushort_t f2bf(float f) {
  union { float f; uint_t u; } v; v.f = f;
  uint_t r = v.u + 0x7FFF + ((v.u >> 16) & 1);   // RNE
  return (ushort_t)(r >> 16);
}
__device__ __forceinline__ float bf2f(uint_t hi16) {
  union { uint_t u; float f; } v; v.u = hi16 << 16;
  return v.f;
}
__device__ __forceinline__ uint_t pack2(float a, float b) {
  return (uint_t)f2bf(a) | ((uint_t)f2bf(b) << 16);
}

// ---------------- CSR build ----------------
__global__ void deg_kernel(const int* __restrict__ ei, int* __restrict__ deg) {
  int e = blockIdx.x * 256 + threadIdx.x;
  if (e >= ETOT) return;
  int dst = (e < EE) ? ei[EE + e] : (e - EE);
  atomicAdd(&deg[dst], 1);
}

// single-block exclusive scan of deg[NN] -> rowptr[NN+1]
__global__ void scan_kernel(const int* __restrict__ deg, int* __restrict__ rowptr) {
  __shared__ int wsum[16];
  __shared__ int carry_s;
  const int tid = threadIdx.x;           // blockDim = 1024
  const int lane = tid & 63, wid = tid >> 6;
  if (tid == 0) carry_s = 0;
  __syncthreads();
  for (int base = 0; base < NN; base += 1024) {
    int i = base + tid;
    int v = (i < NN) ? deg[i] : 0;
    int x = v;
    #pragma unroll
    for (int off = 1; off < 64; off <<= 1) {
      int y = __shfl_up(x, off, 64);
      if (lane >= off) x += y;
    }
    if (lane == 63) wsum[wid] = x;
    __syncthreads();
    if (tid < 64) {
      int w = (tid < 16) ? wsum[tid] : 0;
      #pragma unroll
      for (int off = 1; off < 16; off <<= 1) {
        int y = __shfl_up(w, off, 64);
        if (lane >= off) w += y;
      }
      if (tid < 16) wsum[tid] = w;   // inclusive prefix of wave sums
    }
    __syncthreads();
    int incl = x + (wid > 0 ? wsum[wid - 1] : 0);
    int carry = carry_s;
    if (i < NN) rowptr[i] = carry + incl - v;   // exclusive
    __syncthreads();
    if (tid == 1023) carry_s = carry + incl;    // chunk total
    __syncthreads();
  }
  if (tid == 0) rowptr[NN] = carry_s;
}

__global__ void fill_kernel(const int* __restrict__ ei, int* __restrict__ cursor,
                            int* __restrict__ csr_src) {
  int e = blockIdx.x * 256 + threadIdx.x;
  if (e >= ETOT) return;
  int src, dst;
  if (e < EE) { src = ei[e]; dst = ei[EE + e]; } else { src = dst = e - EE; }
  int slot = atomicAdd(&cursor[dst], 1);
  csr_src[slot] = src;
}

// ---------------- weights fp32 -> bf16 (once per launch) ----------------
__global__ void w2bf_kernel(const float* __restrict__ W0, const float* __restrict__ W1,
                            const float* __restrict__ W2, const float* __restrict__ W3,
                            ushort_t* __restrict__ dst) {
  int i = blockIdx.x * 256 + threadIdx.x;          // 147456 total
  if (i < 65536) dst[i] = f2bf(W0[i]);
  else if (i < 131072) dst[i] = f2bf(W1[i - 65536]);
  else if (i < 139264) dst[i] = f2bf(W2[i - 131072]);
  else if (i < 147456) dst[i] = f2bf(W3[i - 139264]);
}

// ---------------- layer-1 linear (K=4), both Wl and Wr, bf16 outputs ----------------
__global__ void lin1_both(const float* __restrict__ x,
                          const float* __restrict__ Wl, const float* __restrict__ bl,
                          const float* __restrict__ Wr, const float* __restrict__ br,
                          ushort_t* __restrict__ xl, ushort_t* __restrict__ xr) {
  int i = blockIdx.x * 256 + threadIdx.x;          // NN*256 total
  int n = i >> 8, o = i & 255;
  float4 xv = *reinterpret_cast<const float4*>(x + (size_t)n * 4);
  float4 wl = *reinterpret_cast<const float4*>(Wl + (size_t)o * 4);
  float4 wr = *reinterpret_cast<const float4*>(Wr + (size_t)o * 4);
  xl[i] = f2bf(wl.x * xv.x + wl.y * xv.y + wl.z * xv.z + wl.w * xv.w + bl[o]);
  xr[i] = f2bf(wr.x * xv.x + wr.y * xv.y + wr.z * xv.z + wr.w * xv.w + br[o]);
}

// ---------------- MFMA bf16 GEMM: Y[M][N] = X[M][256] * W[N][256]^T + b, bf16 out ----
// wave tile 64x16 (4 stacked 16x16x32 MFMAs); WMW x WNW waves per block.
template<int N, int WMW, int WNW>
__global__ __launch_bounds__(WMW * WNW * 64) void gemm_mfma(
    const ushort_t* __restrict__ X, const ushort_t* __restrict__ Wb,
    const float* __restrict__ bias, ushort_t* __restrict__ Y, int M) {
  const int wave = threadIdx.x >> 6;
  const int lane = threadIdx.x & 63;
  const int wm = wave / WNW, wn = wave % WNW;
  const int r16 = lane & 15;
  const int m0 = blockIdx.x * (WMW * 64) + wm * 64;
  const int ncol = blockIdx.y * (WNW * 16) + wn * 16 + r16;
  const int koff = (lane >> 4) * 8;
  f32x4 acc0 = {0.f,0.f,0.f,0.f}, acc1 = {0.f,0.f,0.f,0.f};
  f32x4 acc2 = {0.f,0.f,0.f,0.f}, acc3 = {0.f,0.f,0.f,0.f};
  const ushort_t* xp = X + (size_t)(m0 + r16) * 256 + koff;
  const ushort_t* wp = Wb + (size_t)ncol * 256 + koff;
  #pragma unroll 2
  for (int k0 = 0; k0 < 256; k0 += 32) {
    bf16x8 bf = *reinterpret_cast<const bf16x8*>(wp + k0);
    bf16x8 a0 = *reinterpret_cast<const bf16x8*>(xp + k0);
    bf16x8 a1 = *reinterpret_cast<const bf16x8*>(xp + 16 * 256 + k0);
    bf16x8 a2 = *reinterpret_cast<const bf16x8*>(xp + 32 * 256 + k0);
    bf16x8 a3 = *reinterpret_cast<const bf16x8*>(xp + 48 * 256 + k0);
    acc0 = __builtin_amdgcn_mfma_f32_16x16x32_bf16(a0, bf, acc0, 0, 0, 0);
    acc1 = __builtin_amdgcn_mfma_f32_16x16x32_bf16(a1, bf, acc1, 0, 0, 0);
    acc2 = __builtin_amdgcn_mfma_f32_16x16x32_bf16(a2, bf, acc2, 0, 0, 0);
    acc3 = __builtin_amdgcn_mfma_f32_16x16x32_bf16(a3, bf, acc3, 0, 0, 0);
  }
  const float bv = bias[ncol];
  const int rbase = (lane >> 4) * 4;
  #pragma unroll
  for (int r = 0; r < 4; ++r) {
    int row = m0 + rbase + r;
    if (row < M) Y[(size_t)row * N + ncol] = f2bf(acc0[r] + bv);
    row += 16;
    if (row < M) Y[(size_t)row * N + ncol] = f2bf(acc1[r] + bv);
    row += 16;
    if (row < M) Y[(size_t)row * N + ncol] = f2bf(acc2[r] + bv);
    row += 16;
    if (row < M) Y[(size_t)row * N + ncol] = f2bf(acc3[r] + bv);
  }
}

// ---------------- fused GATv2 attention + aggregation, H=4, C=64, bf16 in/out ------
// 4 nodes per block; one wave per node; lane owns 4 channels (uint2 = 4 bf16).
template<bool BN_ELU>
__global__ __launch_bounds__(256) void fused_agg4(
    const ushort_t* __restrict__ xl, const ushort_t* __restrict__ xr,
    const int* __restrict__ rowptr, const int* __restrict__ csr_src,
    const float* __restrict__ att, const float* __restrict__ bias,
    const float* __restrict__ bn_g, const float* __restrict__ bn_b,
    const float* __restrict__ bn_m, const float* __restrict__ bn_v,
    ushort_t* __restrict__ out) {
  int n = blockIdx.x * 4 + (threadIdx.x >> 6);
  if (n >= NN) return;
  int lane = threadIdx.x & 63;
  uint2 xru = reinterpret_cast<const uint2*>(xr + (size_t)n * 256)[lane];
  float xr0 = bf2f(xru.x & 0xFFFF), xr1 = bf2f(xru.x >> 16);
  float xr2 = bf2f(xru.y & 0xFFFF), xr3 = bf2f(xru.y >> 16);
  float4 atv = reinterpret_cast<const float4*>(att)[lane];
  int beg = rowptr[n], end = rowptr[n + 1];
  float m = -3.4e38f, d = 0.f;
  float a0 = 0.f, a1 = 0.f, a2 = 0.f, a3 = 0.f;
  #pragma unroll 2
  for (int s = beg; s < end; ++s) {
    int src = csr_src[s];
    uint2 xu = reinterpret_cast<const uint2*>(xl + (size_t)src * 256)[lane];
    float x0 = bf2f(xu.x & 0xFFFF), x1 = bf2f(xu.x >> 16);
    float x2 = bf2f(xu.y & 0xFFFF), x3 = bf2f(xu.y >> 16);
    float e0 = x0 + xr0; e0 = (e0 > 0.f) ? e0 : 0.2f * e0;
    float e1 = x1 + xr1; e1 = (e1 > 0.f) ? e1 : 0.2f * e1;
    float e2 = x2 + xr2; e2 = (e2 > 0.f) ? e2 : 0.2f * e2;
    float e3 = x3 + xr3; e3 = (e3 > 0.f) ? e3 : 0.2f * e3;
    float sc = atv.x * e0 + atv.y * e1 + atv.z * e2 + atv.w * e3;
    #pragma unroll
    for (int off = 8; off; off >>= 1) sc += __shfl_xor(sc, off, 64);  // per-head (16-lane) sum
    float mn = fmaxf(m, sc);
    float scale = __expf(m - mn);
    float w = __expf(sc - mn);
    a0 = a0 * scale + w * x0;
    a1 = a1 * scale + w * x1;
    a2 = a2 * scale + w * x2;
    a3 = a3 * scale + w * x3;
    d = d * scale + w;
    m = mn;
  }
  float inv = 1.f / (d + 1e-16f);
  float4 bsv = reinterpret_cast<const float4*>(bias)[lane];
  float v0 = a0 * inv + bsv.x, v1 = a1 * inv + bsv.y;
  float v2 = a2 * inv + bsv.z, v3 = a3 * inv + bsv.w;
  if (BN_ELU) {
    float4 g = reinterpret_cast<const float4*>(bn_g)[lane];
    float4 bb = reinterpret_cast<const float4*>(bn_b)[lane];
    float4 mu = reinterpret_cast<const float4*>(bn_m)[lane];
    float4 va = reinterpret_cast<const float4*>(bn_v)[lane];
    float s0 = g.x * rsqrtf(va.x + 1e-5f), s1 = g.y * rsqrtf(va.y + 1e-5f);
    float s2 = g.z * rsqrtf(va.z + 1e-5f), s3 = g.w * rsqrtf(va.w + 1e-5f);
    v0 = s0 * (v0 - mu.x) + bb.x; v0 = (v0 > 0.f) ? v0 : expm1f(v0);
    v1 = s1 * (v1 - mu.y) + bb.y; v1 = (v1 > 0.f) ? v1 : expm1f(v1);
    v2 = s2 * (v2 - mu.z) + bb.z; v2 = (v2 > 0.f) ? v2 : expm1f(v2);
    v3 = s3 * (v3 - mu.w) + bb.w; v3 = (v3 > 0.f) ? v3 : expm1f(v3);
  }
  uint2 o;
  o.x = pack2(v0, v1);
  o.y = pack2(v2, v3);
  reinterpret_cast<uint2*>(out + (size_t)n * 256)[lane] = o;
}

// ---------------- fused layer 3: H=1, C=32, bias only, bf16 in, fp32 out ----------
__global__ __launch_bounds__(256) void fused_agg3(
    const ushort_t* __restrict__ xl, const ushort_t* __restrict__ xr,
    const int* __restrict__ rowptr, const int* __restrict__ csr_src,
    const float* __restrict__ att, const float* __restrict__ bias,
    float* __restrict__ out) {
  int n = blockIdx.x * 4 + (threadIdx.x >> 6);
  if (n >= NN) return;
  int lane = threadIdx.x & 63;
  int grp = lane >> 4;        // which of 4 edges in flight
  int cl = lane & 15;         // channel pair index
  uint_t xru = reinterpret_cast<const uint_t*>(xr + (size_t)n * 32)[cl];
  float xr0 = bf2f(xru & 0xFFFF), xr1 = bf2f(xru >> 16);
  float2 atv = reinterpret_cast<const float2*>(att)[cl];
  int beg = rowptr[n], end = rowptr[n + 1];
  float m = -3.4e38f, d = 0.f, a0 = 0.f, a1 = 0.f;
  for (int s = beg + grp; s < end; s += 4) {
    int src = csr_src[s];
    uint_t xu = reinterpret_cast<const uint_t*>(xl + (size_t)src * 32)[cl];
    float x0 = bf2f(xu & 0xFFFF), x1 = bf2f(xu >> 16);
    float e0 = x0 + xr0; e0 = (e0 > 0.f) ? e0 : 0.2f * e0;
    float e1 = x1 + xr1; e1 = (e1 > 0.f) ? e1 : 0.2f * e1;
    float sc = atv.x * e0 + atv.y * e1;
    #pragma unroll
    for (int off = 8; off; off >>= 1) sc += __shfl_xor(sc, off, 64);  // 16-lane sum
    float mn = fmaxf(m, sc);
    float scale = __expf(m - mn);
    float w = __expf(sc - mn);
    a0 = a0 * scale + w * x0;
    a1 = a1 * scale + w * x1;
    d = d * scale + w;
    m = mn;
  }
  // merge the 4 per-group online states
  #pragma unroll
  for (int off = 16; off <= 32; off <<= 1) {
    float mo = __shfl_xor(m, off, 64);
    float doo = __shfl_xor(d, off, 64);
    float b0 = __shfl_xor(a0, off, 64);
    float b1 = __shfl_xor(a1, off, 64);
    float mn = fmaxf(m, mo);
    float se = __expf(m - mn), so = __expf(mo - mn);
    a0 = a0 * se + b0 * so;
    a1 = a1 * se + b1 * so;
    d = d * se + doo * so;
    m = mn;
  }
  if (grp == 0) {
    float inv = 1.f / (d + 1e-16f);
    float2 bsv = reinterpret_cast<const float2*>(bias)[cl];
    reinterpret_cast<float2*>(out + (size_t)n * 32)[cl] =
        make_float2(a0 * inv + bsv.x, a1 * inv + bsv.y);
  }
}

extern "C" void kernel_launch(void* const* d_in, const int* in_sizes, int n_in,
                              void* d_out, int out_size, void* d_ws, size_t ws_size,
                              hipStream_t stream) {
  (void)in_sizes; (void)n_in; (void)out_size; (void)ws_size;
  const float* x  = (const float*)d_in[0];
  const int*   ei = (const int*)d_in[1];
  const float *Wl1 = (const float*)d_in[2],  *bl1 = (const float*)d_in[3],
              *Wr1 = (const float*)d_in[4],  *br1 = (const float*)d_in[5],
              *att1 = (const float*)d_in[6], *bias1 = (const float*)d_in[7],
              *g1 = (const float*)d_in[8],   *be1 = (const float*)d_in[9],
              *m1 = (const float*)d_in[10],  *v1 = (const float*)d_in[11];
  const float *Wl2 = (const float*)d_in[12], *bl2 = (const float*)d_in[13],
              *Wr2 = (const float*)d_in[14], *br2 = (const float*)d_in[15],
              *att2 = (const float*)d_in[16], *bias2 = (const float*)d_in[17],
              *g2 = (const float*)d_in[18],  *be2 = (const float*)d_in[19],
              *m2 = (const float*)d_in[20],  *v2 = (const float*)d_in[21];
  const float *Wl3 = (const float*)d_in[22], *bl3 = (const float*)d_in[23],
              *Wr3 = (const float*)d_in[24], *br3 = (const float*)d_in[25],
              *att3 = (const float*)d_in[26], *bias3 = (const float*)d_in[27];
  float* out = (float*)d_out;

  char* p = (char*)d_ws;
  auto alloc = [&](size_t bytes) { char* r = p; p += (bytes + 255) & ~(size_t)255; return r; };
  int*      deg     = (int*)alloc((size_t)NN * 4);
  int*      rowptr  = (int*)alloc((size_t)(NN + 1) * 4);
  int*      cursor  = (int*)alloc((size_t)NN * 4);
  int*      csr_src = (int*)alloc((size_t)ETOT * 4);
  ushort_t* xl      = (ushort_t*)alloc((size_t)NN * 256 * 2);
  ushort_t* xr      = (ushort_t*)alloc((size_t)NN * 256 * 2);
  ushort_t* hbuf    = (ushort_t*)alloc((size_t)NN * 256 * 2);
  ushort_t* Wb      = (ushort_t*)alloc((size_t)147456 * 2);  // also OOB-read slack for hbuf
  ushort_t* Wl2b = Wb, *Wr2b = Wb + 65536, *Wl3b = Wb + 131072, *Wr3b = Wb + 139264;

  // CSR by dst
  hipMemsetAsync(deg, 0, (size_t)NN * 4, stream);
  deg_kernel<<<(ETOT + 255) / 256, 256, 0, stream>>>(ei, deg);
  scan_kernel<<<1, 1024, 0, stream>>>(deg, rowptr);
  hipMemcpyAsync(cursor, rowptr, (size_t)NN * 4, hipMemcpyDeviceToDevice, stream);
  fill_kernel<<<(ETOT + 255) / 256, 256, 0, stream>>>(ei, cursor, csr_src);

  // weights -> bf16
  w2bf_kernel<<<576, 256, 0, stream>>>(Wl2, Wr2, Wl3, Wr3, Wb);

  int nb = (NN + 3) / 4;

  // ---- layer 1: 4 -> 4x64 concat, BN+ELU ----
  lin1_both<<<NN, 256, 0, stream>>>(x, Wl1, bl1, Wr1, br1, xl, xr);
  fused_agg4<true><<<nb, 256, 0, stream>>>(xl, xr, rowptr, csr_src, att1, bias1,
                                           g1, be1, m1, v1, hbuf);

  // ---- layer 2: 256 -> 4x64 concat, BN+ELU ----
  {
    dim3 g((NN + 63) / 64, 4);
    gemm_mfma<256, 1, 4><<<g, 256, 0, stream>>>(hbuf, Wl2b, bl2, xl, NN);
    gemm_mfma<256, 1, 4><<<g, 256, 0, stream>>>(hbuf, Wr2b, br2, xr, NN);
  }
  fused_agg4<true><<<nb, 256, 0, stream>>>(xl, xr, rowptr, csr_src, att2, bias2,
                                           g2, be2, m2, v2, hbuf);

  // ---- layer 3: 256 -> 32, 1 head, mean(=identity) ----
  {
    dim3 g((NN + 127) / 128, 1);
    gemm_mfma<32, 2, 2><<<g, 256, 0, stream>>>(hbuf, Wl3b, bl3, xl, NN);
    gemm_mfma<32, 2, 2><<<g, 256, 0, stream>>>(hbuf, Wr3b, br3, xr, NN);
  }
  fused_agg3<<<nb, 256, 0, stream>>>(xl, xr, rowptr, csr_src, att3, bias3, out);
}

// Round 6
// 243.311 us; speedup vs baseline: 8.9721x; 1.1434x over previous
//
#include <hip/hip_runtime.h>
#include <math.h>

#define NN 20000
#define EE 320000
#define ETOT (EE + NN)   // 340000 edges incl. self loops

typedef unsigned short ushort_t;
typedef unsigned int uint_t;
typedef __attribute__((ext_vector_type(8))) short bf16x8;
typedef __attribute__((ext_vector_type(4))) float f32x4;

__device__ __forceinline__ ushort_t f2bf(float f) {
  union { float f; uint_t u; } v; v.f = f;
  uint_t r = v.u + 0x7FFF + ((v.u >> 16) & 1);   // RNE
  return (ushort_t)(r >> 16);
}
__device__ __forceinline__ float bf2f(uint_t hi16) {
  union { uint_t u; float f; } v; v.u = hi16 << 16;
  return v.f;
}
__device__ __forceinline__ uint_t pack2(float a, float b) {
  return (uint_t)f2bf(a) | ((uint_t)f2bf(b) << 16);
}

// ---------------- CSR build ----------------
__global__ void deg_kernel(const int* __restrict__ ei, int* __restrict__ deg) {
  int e = blockIdx.x * 256 + threadIdx.x;
  if (e >= ETOT) return;
  int dst = (e < EE) ? ei[EE + e] : (e - EE);
  atomicAdd(&deg[dst], 1);
}

// single-block exclusive scan of deg[NN] -> rowptr[NN+1]
__global__ void scan_kernel(const int* __restrict__ deg, int* __restrict__ rowptr) {
  __shared__ int wsum[16];
  __shared__ int carry_s;
  const int tid = threadIdx.x;           // blockDim = 1024
  const int lane = tid & 63, wid = tid >> 6;
  if (tid == 0) carry_s = 0;
  __syncthreads();
  for (int base = 0; base < NN; base += 1024) {
    int i = base + tid;
    int v = (i < NN) ? deg[i] : 0;
    int x = v;
    #pragma unroll
    for (int off = 1; off < 64; off <<= 1) {
      int y = __shfl_up(x, off, 64);
      if (lane >= off) x += y;
    }
    if (lane == 63) wsum[wid] = x;
    __syncthreads();
    if (tid < 64) {
      int w = (tid < 16) ? wsum[tid] : 0;
      #pragma unroll
      for (int off = 1; off < 16; off <<= 1) {
        int y = __shfl_up(w, off, 64);
        if (lane >= off) w += y;
      }
      if (tid < 16) wsum[tid] = w;   // inclusive prefix of wave sums
    }
    __syncthreads();
    int incl = x + (wid > 0 ? wsum[wid - 1] : 0);
    int carry = carry_s;
    if (i < NN) rowptr[i] = carry + incl - v;   // exclusive
    __syncthreads();
    if (tid == 1023) carry_s = carry + incl;    // chunk total
    __syncthreads();
  }
  if (tid == 0) rowptr[NN] = carry_s;
}

__global__ void fill_kernel(const int* __restrict__ ei, int* __restrict__ cursor,
                            int* __restrict__ csr_src) {
  int e = blockIdx.x * 256 + threadIdx.x;
  if (e >= ETOT) return;
  int src, dst;
  if (e < EE) { src = ei[e]; dst = ei[EE + e]; } else { src = dst = e - EE; }
  int slot = atomicAdd(&cursor[dst], 1);
  csr_src[slot] = src;
}

// ---------------- weights fp32 -> bf16 (once per launch) ----------------
// layout: [Wl2(65536) | Wr2(65536) | Wl3(8192) | Wr3(8192)] -> combined GEMM weights
__global__ void w2bf_kernel(const float* __restrict__ W0, const float* __restrict__ W1,
                            const float* __restrict__ W2, const float* __restrict__ W3,
                            ushort_t* __restrict__ dst) {
  int i = blockIdx.x * 256 + threadIdx.x;          // 147456 total
  if (i < 65536) dst[i] = f2bf(W0[i]);
  else if (i < 131072) dst[i] = f2bf(W1[i - 65536]);
  else if (i < 139264) dst[i] = f2bf(W2[i - 131072]);
  else if (i < 147456) dst[i] = f2bf(W3[i - 139264]);
}

// ---------------- layer-1 linear (K=4), writes interleaved xlr[n][512] -------------
__global__ void lin1_both(const float* __restrict__ x,
                          const float* __restrict__ Wl, const float* __restrict__ bl,
                          const float* __restrict__ Wr, const float* __restrict__ br,
                          ushort_t* __restrict__ xlr) {
  int i = blockIdx.x * 256 + threadIdx.x;          // NN*256 total
  int n = i >> 8, o = i & 255;
  float4 xv = *reinterpret_cast<const float4*>(x + (size_t)n * 4);
  float4 wl = *reinterpret_cast<const float4*>(Wl + (size_t)o * 4);
  float4 wr = *reinterpret_cast<const float4*>(Wr + (size_t)o * 4);
  xlr[(size_t)n * 512 + o]       = f2bf(wl.x * xv.x + wl.y * xv.y + wl.z * xv.z + wl.w * xv.w + bl[o]);
  xlr[(size_t)n * 512 + 256 + o] = f2bf(wr.x * xv.x + wr.y * xv.y + wr.z * xv.z + wr.w * xv.w + br[o]);
}

// ---------------- MFMA bf16 GEMM: Y[M][N] = X[M][256] * W[N][256]^T + bias ---------
// W rows [0,NL) use bl, [NL,N) use br. Y row stride = N. X row stride = 256.
// wave tile 64x16 (4 stacked 16x16x32 MFMAs); WMW x WNW waves per block.
template<int N, int NL, int WMW, int WNW>
__global__ __launch_bounds__(WMW * WNW * 64) void gemm_mfma(
    const ushort_t* __restrict__ X, const ushort_t* __restrict__ Wb,
    const float* __restrict__ bl, const float* __restrict__ br,
    ushort_t* __restrict__ Y, int M) {
  const int wave = threadIdx.x >> 6;
  const int lane = threadIdx.x & 63;
  const int wm = wave / WNW, wn = wave % WNW;
  const int r16 = lane & 15;
  const int m0 = blockIdx.x * (WMW * 64) + wm * 64;
  const int ncol = blockIdx.y * (WNW * 16) + wn * 16 + r16;
  const int koff = (lane >> 4) * 8;
  f32x4 acc0 = {0.f,0.f,0.f,0.f}, acc1 = {0.f,0.f,0.f,0.f};
  f32x4 acc2 = {0.f,0.f,0.f,0.f}, acc3 = {0.f,0.f,0.f,0.f};
  const ushort_t* xp = X + (size_t)(m0 + r16) * 256 + koff;
  const ushort_t* wp = Wb + (size_t)ncol * 256 + koff;
  #pragma unroll 2
  for (int k0 = 0; k0 < 256; k0 += 32) {
    bf16x8 bf = *reinterpret_cast<const bf16x8*>(wp + k0);
    bf16x8 a0 = *reinterpret_cast<const bf16x8*>(xp + k0);
    bf16x8 a1 = *reinterpret_cast<const bf16x8*>(xp + 16 * 256 + k0);
    bf16x8 a2 = *reinterpret_cast<const bf16x8*>(xp + 32 * 256 + k0);
    bf16x8 a3 = *reinterpret_cast<const bf16x8*>(xp + 48 * 256 + k0);
    acc0 = __builtin_amdgcn_mfma_f32_16x16x32_bf16(a0, bf, acc0, 0, 0, 0);
    acc1 = __builtin_amdgcn_mfma_f32_16x16x32_bf16(a1, bf, acc1, 0, 0, 0);
    acc2 = __builtin_amdgcn_mfma_f32_16x16x32_bf16(a2, bf, acc2, 0, 0, 0);
    acc3 = __builtin_amdgcn_mfma_f32_16x16x32_bf16(a3, bf, acc3, 0, 0, 0);
  }
  const float bv = (ncol < NL) ? bl[ncol] : br[ncol - NL];
  const int rbase = (lane >> 4) * 4;
  #pragma unroll
  for (int r = 0; r < 4; ++r) {
    int row = m0 + rbase + r;
    if (row < M) Y[(size_t)row * N + ncol] = f2bf(acc0[r] + bv);
    row += 16;
    if (row < M) Y[(size_t)row * N + ncol] = f2bf(acc1[r] + bv);
    row += 16;
    if (row < M) Y[(size_t)row * N + ncol] = f2bf(acc2[r] + bv);
    row += 16;
    if (row < M) Y[(size_t)row * N + ncol] = f2bf(acc3[r] + bv);
  }
}

// ---------------- fused GATv2 attention + aggregation, H=4, C=64 -------------------
// Input xlr[n][512] interleaved (xl at +0, xr at +256). Output hbuf[n][256] bf16.
// 4 nodes per block; one wave per node; lane owns 4 channels.
// Dual online-softmax states: edges s,s+1 update independent states, merged at end.
template<bool BN_ELU>
__global__ __launch_bounds__(256) void fused_agg4(
    const ushort_t* __restrict__ xlr,
    const int* __restrict__ rowptr, const int* __restrict__ csr_src,
    const float* __restrict__ att, const float* __restrict__ bias,
    const float* __restrict__ bn_g, const float* __restrict__ bn_b,
    const float* __restrict__ bn_m, const float* __restrict__ bn_v,
    ushort_t* __restrict__ out) {
  int n = blockIdx.x * 4 + (threadIdx.x >> 6);
  if (n >= NN) return;
  int lane = threadIdx.x & 63;
  uint2 xru = reinterpret_cast<const uint2*>(xlr + (size_t)n * 512 + 256)[lane];
  float xr0 = bf2f(xru.x & 0xFFFF), xr1 = bf2f(xru.x >> 16);
  float xr2 = bf2f(xru.y & 0xFFFF), xr3 = bf2f(xru.y >> 16);
  float4 atv = reinterpret_cast<const float4*>(att)[lane];
  int beg = rowptr[n], end = rowptr[n + 1];

  float mA = -3.4e38f, dA = 0.f, a0 = 0.f, a1 = 0.f, a2 = 0.f, a3 = 0.f;
  float mB = -3.4e38f, dB = 0.f, b0 = 0.f, b1 = 0.f, b2 = 0.f, b3 = 0.f;

  int s = beg;
  for (; s + 2 <= end; s += 2) {
    int src0 = csr_src[s], src1 = csr_src[s + 1];
    uint2 u0 = reinterpret_cast<const uint2*>(xlr + (size_t)src0 * 512)[lane];
    uint2 u1 = reinterpret_cast<const uint2*>(xlr + (size_t)src1 * 512)[lane];
    float p0 = bf2f(u0.x & 0xFFFF), p1 = bf2f(u0.x >> 16);
    float p2 = bf2f(u0.y & 0xFFFF), p3 = bf2f(u0.y >> 16);
    float q0 = bf2f(u1.x & 0xFFFF), q1 = bf2f(u1.x >> 16);
    float q2 = bf2f(u1.y & 0xFFFF), q3 = bf2f(u1.y >> 16);
    float e0 = p0 + xr0; e0 = (e0 > 0.f) ? e0 : 0.2f * e0;
    float e1 = p1 + xr1; e1 = (e1 > 0.f) ? e1 : 0.2f * e1;
    float e2 = p2 + xr2; e2 = (e2 > 0.f) ? e2 : 0.2f * e2;
    float e3 = p3 + xr3; e3 = (e3 > 0.f) ? e3 : 0.2f * e3;
    float f0 = q0 + xr0; f0 = (f0 > 0.f) ? f0 : 0.2f * f0;
    float f1 = q1 + xr1; f1 = (f1 > 0.f) ? f1 : 0.2f * f1;
    float f2 = q2 + xr2; f2 = (f2 > 0.f) ? f2 : 0.2f * f2;
    float f3 = q3 + xr3; f3 = (f3 > 0.f) ? f3 : 0.2f * f3;
    float scA = atv.x * e0 + atv.y * e1 + atv.z * e2 + atv.w * e3;
    float scB = atv.x * f0 + atv.y * f1 + atv.z * f2 + atv.w * f3;
    #pragma unroll
    for (int off = 8; off; off >>= 1) {
      scA += __shfl_xor(scA, off, 64);   // per-head (16-lane) sums, two
      scB += __shfl_xor(scB, off, 64);   // independent chains
    }
    float mnA = fmaxf(mA, scA);
    float mnB = fmaxf(mB, scB);
    float sclA = __expf(mA - mnA), wA = __expf(scA - mnA);
    float sclB = __expf(mB - mnB), wB = __expf(scB - mnB);
    a0 = a0 * sclA + wA * p0; b0 = b0 * sclB + wB * q0;
    a1 = a1 * sclA + wA * p1; b1 = b1 * sclB + wB * q1;
    a2 = a2 * sclA + wA * p2; b2 = b2 * sclB + wB * q2;
    a3 = a3 * sclA + wA * p3; b3 = b3 * sclB + wB * q3;
    dA = dA * sclA + wA;      dB = dB * sclB + wB;
    mA = mnA;                 mB = mnB;
  }
  if (s < end) {   // odd remainder -> state A
    int src0 = csr_src[s];
    uint2 u0 = reinterpret_cast<const uint2*>(xlr + (size_t)src0 * 512)[lane];
    float p0 = bf2f(u0.x & 0xFFFF), p1 = bf2f(u0.x >> 16);
    float p2 = bf2f(u0.y & 0xFFFF), p3 = bf2f(u0.y >> 16);
    float e0 = p0 + xr0; e0 = (e0 > 0.f) ? e0 : 0.2f * e0;
    float e1 = p1 + xr1; e1 = (e1 > 0.f) ? e1 : 0.2f * e1;
    float e2 = p2 + xr2; e2 = (e2 > 0.f) ? e2 : 0.2f * e2;
    float e3 = p3 + xr3; e3 = (e3 > 0.f) ? e3 : 0.2f * e3;
    float scA = atv.x * e0 + atv.y * e1 + atv.z * e2 + atv.w * e3;
    #pragma unroll
    for (int off = 8; off; off >>= 1) scA += __shfl_xor(scA, off, 64);
    float mnA = fmaxf(mA, scA);
    float sclA = __expf(mA - mnA), wA = __expf(scA - mnA);
    a0 = a0 * sclA + wA * p0;
    a1 = a1 * sclA + wA * p1;
    a2 = a2 * sclA + wA * p2;
    a3 = a3 * sclA + wA * p3;
    dA = dA * sclA + wA;
    mA = mnA;
  }
  // merge state B into state A (B may be empty: dB==0, exp(-inf-mn)=0 is safe
  // only if mn finite; guard with dB check)
  if (dB > 0.f) {
    float mn = fmaxf(mA, mB);
    float sA = __expf(mA - mn), sB = __expf(mB - mn);
    a0 = a0 * sA + b0 * sB;
    a1 = a1 * sA + b1 * sB;
    a2 = a2 * sA + b2 * sB;
    a3 = a3 * sA + b3 * sB;
    dA = dA * sA + dB * sB;
  }
  float inv = 1.f / (dA + 1e-16f);
  float4 bsv = reinterpret_cast<const float4*>(bias)[lane];
  float v0 = a0 * inv + bsv.x, v1 = a1 * inv + bsv.y;
  float v2 = a2 * inv + bsv.z, v3 = a3 * inv + bsv.w;
  if (BN_ELU) {
    float4 g = reinterpret_cast<const float4*>(bn_g)[lane];
    float4 bb = reinterpret_cast<const float4*>(bn_b)[lane];
    float4 mu = reinterpret_cast<const float4*>(bn_m)[lane];
    float4 va = reinterpret_cast<const float4*>(bn_v)[lane];
    float s0 = g.x * rsqrtf(va.x + 1e-5f), s1 = g.y * rsqrtf(va.y + 1e-5f);
    float s2 = g.z * rsqrtf(va.z + 1e-5f), s3 = g.w * rsqrtf(va.w + 1e-5f);
    v0 = s0 * (v0 - mu.x) + bb.x; v0 = (v0 > 0.f) ? v0 : expm1f(v0);
    v1 = s1 * (v1 - mu.y) + bb.y; v1 = (v1 > 0.f) ? v1 : expm1f(v1);
    v2 = s2 * (v2 - mu.z) + bb.z; v2 = (v2 > 0.f) ? v2 : expm1f(v2);
    v3 = s3 * (v3 - mu.w) + bb.w; v3 = (v3 > 0.f) ? v3 : expm1f(v3);
  }
  uint2 o;
  o.x = pack2(v0, v1);
  o.y = pack2(v2, v3);
  reinterpret_cast<uint2*>(out + (size_t)n * 256)[lane] = o;
}

// ---------------- fused layer 3: H=1, C=32, bias only ------------------------------
// Input xlr[n][64] interleaved (xl at +0, xr at +32). Output fp32.
// 4 nodes per block; wave per node; 16 lanes per edge (2 ch/lane), 4 edges in flight.
__global__ __launch_bounds__(256) void fused_agg3(
    const ushort_t* __restrict__ xlr,
    const int* __restrict__ rowptr, const int* __restrict__ csr_src,
    const float* __restrict__ att, const float* __restrict__ bias,
    float* __restrict__ out) {
  int n = blockIdx.x * 4 + (threadIdx.x >> 6);
  if (n >= NN) return;
  int lane = threadIdx.x & 63;
  int grp = lane >> 4;        // which of 4 edges in flight
  int cl = lane & 15;         // channel pair index
  uint_t xru = reinterpret_cast<const uint_t*>(xlr + (size_t)n * 64 + 32)[cl];
  float xr0 = bf2f(xru & 0xFFFF), xr1 = bf2f(xru >> 16);
  float2 atv = reinterpret_cast<const float2*>(att)[cl];
  int beg = rowptr[n], end = rowptr[n + 1];
  float m = -3.4e38f, d = 0.f, a0 = 0.f, a1 = 0.f;
  for (int s = beg + grp; s < end; s += 4) {
    int src = csr_src[s];
    uint_t xu = reinterpret_cast<const uint_t*>(xlr + (size_t)src * 64)[cl];
    float x0 = bf2f(xu & 0xFFFF), x1 = bf2f(xu >> 16);
    float e0 = x0 + xr0; e0 = (e0 > 0.f) ? e0 : 0.2f * e0;
    float e1 = x1 + xr1; e1 = (e1 > 0.f) ? e1 : 0.2f * e1;
    float sc = atv.x * e0 + atv.y * e1;
    #pragma unroll
    for (int off = 8; off; off >>= 1) sc += __shfl_xor(sc, off, 64);  // 16-lane sum
    float mn = fmaxf(m, sc);
    float scale = __expf(m - mn);
    float w = __expf(sc - mn);
    a0 = a0 * scale + w * x0;
    a1 = a1 * scale + w * x1;
    d = d * scale + w;
    m = mn;
  }
  // merge the 4 per-group online states (some may be empty; guard via d)
  #pragma unroll
  for (int off = 16; off <= 32; off <<= 1) {
    float mo = __shfl_xor(m, off, 64);
    float doo = __shfl_xor(d, off, 64);
    float c0 = __shfl_xor(a0, off, 64);
    float c1 = __shfl_xor(a1, off, 64);
    if (doo > 0.f) {
      if (d > 0.f) {
        float mn = fmaxf(m, mo);
        float se = __expf(m - mn), so = __expf(mo - mn);
        a0 = a0 * se + c0 * so;
        a1 = a1 * se + c1 * so;
        d = d * se + doo * so;
        m = mn;
      } else {
        a0 = c0; a1 = c1; d = doo; m = mo;
      }
    }
  }
  if (grp == 0) {
    float inv = 1.f / (d + 1e-16f);
    float2 bsv = reinterpret_cast<const float2*>(bias)[cl];
    reinterpret_cast<float2*>(out + (size_t)n * 32)[cl] =
        make_float2(a0 * inv + bsv.x, a1 * inv + bsv.y);
  }
}

extern "C" void kernel_launch(void* const* d_in, const int* in_sizes, int n_in,
                              void* d_out, int out_size, void* d_ws, size_t ws_size,
                              hipStream_t stream) {
  (void)in_sizes; (void)n_in; (void)out_size; (void)ws_size;
  const float* x  = (const float*)d_in[0];
  const int*   ei = (const int*)d_in[1];
  const float *Wl1 = (const float*)d_in[2],  *bl1 = (const float*)d_in[3],
              *Wr1 = (const float*)d_in[4],  *br1 = (const float*)d_in[5],
              *att1 = (const float*)d_in[6], *bias1 = (const float*)d_in[7],
              *g1 = (const float*)d_in[8],   *be1 = (const float*)d_in[9],
              *m1 = (const float*)d_in[10],  *v1 = (const float*)d_in[11];
  const float *Wl2 = (const float*)d_in[12], *bl2 = (const float*)d_in[13],
              *Wr2 = (const float*)d_in[14], *br2 = (const float*)d_in[15],
              *att2 = (const float*)d_in[16], *bias2 = (const float*)d_in[17],
              *g2 = (const float*)d_in[18],  *be2 = (const float*)d_in[19],
              *m2 = (const float*)d_in[20],  *v2 = (const float*)d_in[21];
  const float *Wl3 = (const float*)d_in[22], *bl3 = (const float*)d_in[23],
              *Wr3 = (const float*)d_in[24], *br3 = (const float*)d_in[25],
              *att3 = (const float*)d_in[26], *bias3 = (const float*)d_in[27];
  float* out = (float*)d_out;

  char* p = (char*)d_ws;
  auto alloc = [&](size_t bytes) { char* r = p; p += (bytes + 255) & ~(size_t)255; return r; };
  int*      deg     = (int*)alloc((size_t)NN * 4);
  int*      rowptr  = (int*)alloc((size_t)(NN + 1) * 4);
  int*      cursor  = (int*)alloc((size_t)NN * 4);
  int*      csr_src = (int*)alloc((size_t)ETOT * 4);
  ushort_t* xlr     = (ushort_t*)alloc((size_t)NN * 512 * 2);   // interleaved xl|xr
  ushort_t* hbuf    = (ushort_t*)alloc((size_t)NN * 256 * 2);
  ushort_t* Wb      = (ushort_t*)alloc((size_t)147456 * 2);     // also OOB-read slack for hbuf
  (void)alloc(4096);                                            // tail slack

  // CSR by dst
  hipMemsetAsync(deg, 0, (size_t)NN * 4, stream);
  deg_kernel<<<(ETOT + 255) / 256, 256, 0, stream>>>(ei, deg);
  scan_kernel<<<1, 1024, 0, stream>>>(deg, rowptr);
  hipMemcpyAsync(cursor, rowptr, (size_t)NN * 4, hipMemcpyDeviceToDevice, stream);
  fill_kernel<<<(ETOT + 255) / 256, 256, 0, stream>>>(ei, cursor, csr_src);

  // weights -> bf16 (combined [Wl2|Wr2] rows 0..511, [Wl3|Wr3] rows 0..63)
  w2bf_kernel<<<576, 256, 0, stream>>>(Wl2, Wr2, Wl3, Wr3, Wb);

  int nb = (NN + 3) / 4;

  // ---- layer 1: 4 -> 4x64 concat, BN+ELU ----
  lin1_both<<<NN, 256, 0, stream>>>(x, Wl1, bl1, Wr1, br1, xlr);
  fused_agg4<true><<<nb, 256, 0, stream>>>(xlr, rowptr, csr_src, att1, bias1,
                                           g1, be1, m1, v1, hbuf);

  // ---- layer 2: 256 -> 4x64 concat (l and r in one N=512 GEMM), BN+ELU ----
  {
    dim3 g((NN + 63) / 64, 8);   // 64 rows x 64 cols per block
    gemm_mfma<512, 256, 1, 4><<<g, 256, 0, stream>>>(hbuf, Wb, bl2, br2, xlr, NN);
  }
  fused_agg4<true><<<nb, 256, 0, stream>>>(xlr, rowptr, csr_src, att2, bias2,
                                           g2, be2, m2, v2, hbuf);

  // ---- layer 3: 256 -> 32, 1 head (l and r in one N=64 GEMM) ----
  {
    dim3 g((NN + 127) / 128, 2); // 128 rows x 32 cols per block
    gemm_mfma<64, 32, 2, 2><<<g, 256, 0, stream>>>(hbuf, Wb + 131072, bl3, br3, xlr, NN);
  }
  fused_agg3<<<nb, 256, 0, stream>>>(xlr, rowptr, csr_src, att3, bias3, out);
}

// Round 7
// 234.823 us; speedup vs baseline: 9.2964x; 1.0361x over previous
//
#include <hip/hip_runtime.h>
#include <math.h>

#define NN 20000
#define EE 320000
#define ETOT (EE + NN)   // 340000 edges incl. self loops

typedef unsigned short ushort_t;
typedef unsigned int uint_t;
typedef __attribute__((ext_vector_type(8))) short bf16x8;
typedef __attribute__((ext_vector_type(4))) float f32x4;

__device__ __forceinline__ ushort_t f2bf(float f) {
  union { float f; uint_t u; } v; v.f = f;
  uint_t r = v.u + 0x7FFF + ((v.u >> 16) & 1);   // RNE
  return (ushort_t)(r >> 16);
}
__device__ __forceinline__ float bf2f(uint_t hi16) {
  union { uint_t u; float f; } v; v.u = hi16 << 16;
  return v.f;
}
__device__ __forceinline__ uint_t pack2(float a, float b) {
  return (uint_t)f2bf(a) | ((uint_t)f2bf(b) << 16);
}

// ---------------- CSR build ----------------
__global__ void deg_kernel(const int* __restrict__ ei, int* __restrict__ deg) {
  int e = blockIdx.x * 256 + threadIdx.x;
  if (e >= ETOT) return;
  int dst = (e < EE) ? ei[EE + e] : (e - EE);
  atomicAdd(&deg[dst], 1);
}

// single-block exclusive scan of deg[NN] -> rowptr[NN+1]
__global__ void scan_kernel(const int* __restrict__ deg, int* __restrict__ rowptr) {
  __shared__ int wsum[16];
  __shared__ int carry_s;
  const int tid = threadIdx.x;           // blockDim = 1024
  const int lane = tid & 63, wid = tid >> 6;
  if (tid == 0) carry_s = 0;
  __syncthreads();
  for (int base = 0; base < NN; base += 1024) {
    int i = base + tid;
    int v = (i < NN) ? deg[i] : 0;
    int x = v;
    #pragma unroll
    for (int off = 1; off < 64; off <<= 1) {
      int y = __shfl_up(x, off, 64);
      if (lane >= off) x += y;
    }
    if (lane == 63) wsum[wid] = x;
    __syncthreads();
    if (tid < 64) {
      int w = (tid < 16) ? wsum[tid] : 0;
      #pragma unroll
      for (int off = 1; off < 16; off <<= 1) {
        int y = __shfl_up(w, off, 64);
        if (lane >= off) w += y;
      }
      if (tid < 16) wsum[tid] = w;   // inclusive prefix of wave sums
    }
    __syncthreads();
    int incl = x + (wid > 0 ? wsum[wid - 1] : 0);
    int carry = carry_s;
    if (i < NN) rowptr[i] = carry + incl - v;   // exclusive
    __syncthreads();
    if (tid == 1023) carry_s = carry + incl;    // chunk total
    __syncthreads();
  }
  if (tid == 0) rowptr[NN] = carry_s;
}

__global__ void fill_kernel(const int* __restrict__ ei, int* __restrict__ cursor,
                            int* __restrict__ csr_src) {
  int e = blockIdx.x * 256 + threadIdx.x;
  if (e >= ETOT) return;
  int src, dst;
  if (e < EE) { src = ei[e]; dst = ei[EE + e]; } else { src = dst = e - EE; }
  int slot = atomicAdd(&cursor[dst], 1);
  csr_src[slot] = src;
}

// ---------------- weights fp32 -> bf16 (once per launch) ----------------
// layout: [Wl2(65536) | Wr2(65536) | Wl3(8192) | Wr3(8192)] -> combined GEMM weights
__global__ void w2bf_kernel(const float* __restrict__ W0, const float* __restrict__ W1,
                            const float* __restrict__ W2, const float* __restrict__ W3,
                            ushort_t* __restrict__ dst) {
  int i = blockIdx.x * 256 + threadIdx.x;          // 147456 total
  if (i < 65536) dst[i] = f2bf(W0[i]);
  else if (i < 131072) dst[i] = f2bf(W1[i - 65536]);
  else if (i < 139264) dst[i] = f2bf(W2[i - 131072]);
  else if (i < 147456) dst[i] = f2bf(W3[i - 139264]);
}

// ---------------- layer-1 linear (K=4), writes interleaved xlr[n][512] -------------
__global__ void lin1_both(const float* __restrict__ x,
                          const float* __restrict__ Wl, const float* __restrict__ bl,
                          const float* __restrict__ Wr, const float* __restrict__ br,
                          ushort_t* __restrict__ xlr) {
  int i = blockIdx.x * 256 + threadIdx.x;          // NN*256 total
  int n = i >> 8, o = i & 255;
  float4 xv = *reinterpret_cast<const float4*>(x + (size_t)n * 4);
  float4 wl = *reinterpret_cast<const float4*>(Wl + (size_t)o * 4);
  float4 wr = *reinterpret_cast<const float4*>(Wr + (size_t)o * 4);
  xlr[(size_t)n * 512 + o]       = f2bf(wl.x * xv.x + wl.y * xv.y + wl.z * xv.z + wl.w * xv.w + bl[o]);
  xlr[(size_t)n * 512 + 256 + o] = f2bf(wr.x * xv.x + wr.y * xv.y + wr.z * xv.z + wr.w * xv.w + br[o]);
}

// ---------------- MFMA bf16 GEMM: Y[M][N] = X[M][256] * W[N][256]^T + bias ---------
// Wave tile 64x64: 4x4 grid of 16x16x32 MFMAs, next-k operands prefetched into
// registers so loads of step k+1 overlap the 16 MFMAs of step k.
// W rows [0,NL) use bl, [NL,N) use br. Y row stride = N. X row stride = 256.
template<int N, int NL, int WMW, int WNW>
__global__ __launch_bounds__(WMW * WNW * 64) void gemm_mfma(
    const ushort_t* __restrict__ X, const ushort_t* __restrict__ Wb,
    const float* __restrict__ bl, const float* __restrict__ br,
    ushort_t* __restrict__ Y, int M) {
  const int wave = threadIdx.x >> 6;
  const int lane = threadIdx.x & 63;
  const int wm = wave / WNW, wn = wave % WNW;
  const int r16 = lane & 15;
  const int koff = (lane >> 4) * 8;
  const int m0 = blockIdx.x * (WMW * 64) + wm * 64;
  const int nb = blockIdx.y * (WNW * 64) + wn * 64;

  const ushort_t* xp = X + (size_t)(m0 + r16) * 256 + koff;
  const ushort_t* wp = Wb + (size_t)(nb + r16) * 256 + koff;

  f32x4 acc[4][4] = {};
  bf16x8 A[4], B[4], An[4], Bn[4];
  #pragma unroll
  for (int i = 0; i < 4; ++i) {
    A[i] = *reinterpret_cast<const bf16x8*>(xp + i * 16 * 256);
    B[i] = *reinterpret_cast<const bf16x8*>(wp + i * 16 * 256);
  }
  #pragma unroll
  for (int t = 0; t < 8; ++t) {
    if (t < 7) {
      const int k0 = (t + 1) * 32;
      #pragma unroll
      for (int i = 0; i < 4; ++i) {
        An[i] = *reinterpret_cast<const bf16x8*>(xp + i * 16 * 256 + k0);
        Bn[i] = *reinterpret_cast<const bf16x8*>(wp + i * 16 * 256 + k0);
      }
    }
    #pragma unroll
    for (int i = 0; i < 4; ++i)
      #pragma unroll
      for (int j = 0; j < 4; ++j)
        acc[i][j] = __builtin_amdgcn_mfma_f32_16x16x32_bf16(A[i], B[j], acc[i][j], 0, 0, 0);
    #pragma unroll
    for (int i = 0; i < 4; ++i) { A[i] = An[i]; B[i] = Bn[i]; }
  }

  const int rbase = (lane >> 4) * 4;
  #pragma unroll
  for (int j = 0; j < 4; ++j) {
    const int ncol = nb + j * 16 + r16;
    const float bv = (ncol < NL) ? bl[ncol] : br[ncol - NL];
    #pragma unroll
    for (int i = 0; i < 4; ++i) {
      #pragma unroll
      for (int r = 0; r < 4; ++r) {
        int row = m0 + i * 16 + rbase + r;
        if (row < M) Y[(size_t)row * N + ncol] = f2bf(acc[i][j][r] + bv);
      }
    }
  }
}

// ---------------- fused GATv2 attention + aggregation, H=4, C=64 -------------------
// Input xlr[n][512] interleaved (xl at +0, xr at +256). Output hbuf[n][256] bf16.
// 4 nodes per block; one wave per node; lane owns 4 channels.
// Dual online-softmax states: edges s,s+1 update independent states, merged at end.
template<bool BN_ELU>
__global__ __launch_bounds__(256) void fused_agg4(
    const ushort_t* __restrict__ xlr,
    const int* __restrict__ rowptr, const int* __restrict__ csr_src,
    const float* __restrict__ att, const float* __restrict__ bias,
    const float* __restrict__ bn_g, const float* __restrict__ bn_b,
    const float* __restrict__ bn_m, const float* __restrict__ bn_v,
    ushort_t* __restrict__ out) {
  int n = blockIdx.x * 4 + (threadIdx.x >> 6);
  if (n >= NN) return;
  int lane = threadIdx.x & 63;
  uint2 xru = reinterpret_cast<const uint2*>(xlr + (size_t)n * 512 + 256)[lane];
  float xr0 = bf2f(xru.x & 0xFFFF), xr1 = bf2f(xru.x >> 16);
  float xr2 = bf2f(xru.y & 0xFFFF), xr3 = bf2f(xru.y >> 16);
  float4 atv = reinterpret_cast<const float4*>(att)[lane];
  int beg = rowptr[n], end = rowptr[n + 1];

  float mA = -3.4e38f, dA = 0.f, a0 = 0.f, a1 = 0.f, a2 = 0.f, a3 = 0.f;
  float mB = -3.4e38f, dB = 0.f, b0 = 0.f, b1 = 0.f, b2 = 0.f, b3 = 0.f;

  int s = beg;
  for (; s + 2 <= end; s += 2) {
    int src0 = csr_src[s], src1 = csr_src[s + 1];
    uint2 u0 = reinterpret_cast<const uint2*>(xlr + (size_t)src0 * 512)[lane];
    uint2 u1 = reinterpret_cast<const uint2*>(xlr + (size_t)src1 * 512)[lane];
    float p0 = bf2f(u0.x & 0xFFFF), p1 = bf2f(u0.x >> 16);
    float p2 = bf2f(u0.y & 0xFFFF), p3 = bf2f(u0.y >> 16);
    float q0 = bf2f(u1.x & 0xFFFF), q1 = bf2f(u1.x >> 16);
    float q2 = bf2f(u1.y & 0xFFFF), q3 = bf2f(u1.y >> 16);
    float e0 = p0 + xr0; e0 = (e0 > 0.f) ? e0 : 0.2f * e0;
    float e1 = p1 + xr1; e1 = (e1 > 0.f) ? e1 : 0.2f * e1;
    float e2 = p2 + xr2; e2 = (e2 > 0.f) ? e2 : 0.2f * e2;
    float e3 = p3 + xr3; e3 = (e3 > 0.f) ? e3 : 0.2f * e3;
    float f0 = q0 + xr0; f0 = (f0 > 0.f) ? f0 : 0.2f * f0;
    float f1 = q1 + xr1; f1 = (f1 > 0.f) ? f1 : 0.2f * f1;
    float f2 = q2 + xr2; f2 = (f2 > 0.f) ? f2 : 0.2f * f2;
    float f3 = q3 + xr3; f3 = (f3 > 0.f) ? f3 : 0.2f * f3;
    float scA = atv.x * e0 + atv.y * e1 + atv.z * e2 + atv.w * e3;
    float scB = atv.x * f0 + atv.y * f1 + atv.z * f2 + atv.w * f3;
    #pragma unroll
    for (int off = 8; off; off >>= 1) {
      scA += __shfl_xor(scA, off, 64);   // per-head (16-lane) sums, two
      scB += __shfl_xor(scB, off, 64);   // independent chains
    }
    float mnA = fmaxf(mA, scA);
    float mnB = fmaxf(mB, scB);
    float sclA = __expf(mA - mnA), wA = __expf(scA - mnA);
    float sclB = __expf(mB - mnB), wB = __expf(scB - mnB);
    a0 = a0 * sclA + wA * p0; b0 = b0 * sclB + wB * q0;
    a1 = a1 * sclA + wA * p1; b1 = b1 * sclB + wB * q1;
    a2 = a2 * sclA + wA * p2; b2 = b2 * sclB + wB * q2;
    a3 = a3 * sclA + wA * p3; b3 = b3 * sclB + wB * q3;
    dA = dA * sclA + wA;      dB = dB * sclB + wB;
    mA = mnA;                 mB = mnB;
  }
  if (s < end) {   // odd remainder -> state A
    int src0 = csr_src[s];
    uint2 u0 = reinterpret_cast<const uint2*>(xlr + (size_t)src0 * 512)[lane];
    float p0 = bf2f(u0.x & 0xFFFF), p1 = bf2f(u0.x >> 16);
    float p2 = bf2f(u0.y & 0xFFFF), p3 = bf2f(u0.y >> 16);
    float e0 = p0 + xr0; e0 = (e0 > 0.f) ? e0 : 0.2f * e0;
    float e1 = p1 + xr1; e1 = (e1 > 0.f) ? e1 : 0.2f * e1;
    float e2 = p2 + xr2; e2 = (e2 > 0.f) ? e2 : 0.2f * e2;
    float e3 = p3 + xr3; e3 = (e3 > 0.f) ? e3 : 0.2f * e3;
    float scA = atv.x * e0 + atv.y * e1 + atv.z * e2 + atv.w * e3;
    #pragma unroll
    for (int off = 8; off; off >>= 1) scA += __shfl_xor(scA, off, 64);
    float mnA = fmaxf(mA, scA);
    float sclA = __expf(mA - mnA), wA = __expf(scA - mnA);
    a0 = a0 * sclA + wA * p0;
    a1 = a1 * sclA + wA * p1;
    a2 = a2 * sclA + wA * p2;
    a3 = a3 * sclA + wA * p3;
    dA = dA * sclA + wA;
    mA = mnA;
  }
  // merge state B into state A (guard: B may be empty)
  if (dB > 0.f) {
    float mn = fmaxf(mA, mB);
    float sA = __expf(mA - mn), sB = __expf(mB - mn);
    a0 = a0 * sA + b0 * sB;
    a1 = a1 * sA + b1 * sB;
    a2 = a2 * sA + b2 * sB;
    a3 = a3 * sA + b3 * sB;
    dA = dA * sA + dB * sB;
  }
  float inv = 1.f / (dA + 1e-16f);
  float4 bsv = reinterpret_cast<const float4*>(bias)[lane];
  float v0 = a0 * inv + bsv.x, v1 = a1 * inv + bsv.y;
  float v2 = a2 * inv + bsv.z, v3 = a3 * inv + bsv.w;
  if (BN_ELU) {
    float4 g = reinterpret_cast<const float4*>(bn_g)[lane];
    float4 bb = reinterpret_cast<const float4*>(bn_b)[lane];
    float4 mu = reinterpret_cast<const float4*>(bn_m)[lane];
    float4 va = reinterpret_cast<const float4*>(bn_v)[lane];
    float s0 = g.x * rsqrtf(va.x + 1e-5f), s1 = g.y * rsqrtf(va.y + 1e-5f);
    float s2 = g.z * rsqrtf(va.z + 1e-5f), s3 = g.w * rsqrtf(va.w + 1e-5f);
    v0 = s0 * (v0 - mu.x) + bb.x; v0 = (v0 > 0.f) ? v0 : expm1f(v0);
    v1 = s1 * (v1 - mu.y) + bb.y; v1 = (v1 > 0.f) ? v1 : expm1f(v1);
    v2 = s2 * (v2 - mu.z) + bb.z; v2 = (v2 > 0.f) ? v2 : expm1f(v2);
    v3 = s3 * (v3 - mu.w) + bb.w; v3 = (v3 > 0.f) ? v3 : expm1f(v3);
  }
  uint2 o;
  o.x = pack2(v0, v1);
  o.y = pack2(v2, v3);
  reinterpret_cast<uint2*>(out + (size_t)n * 256)[lane] = o;
}

// ---------------- fused layer 3: H=1, C=32, bias only ------------------------------
// Input xlr[n][64] interleaved (xl at +0, xr at +32). Output fp32.
// 4 nodes per block; wave per node; 16 lanes per edge (2 ch/lane), 4 edges in flight.
__global__ __launch_bounds__(256) void fused_agg3(
    const ushort_t* __restrict__ xlr,
    const int* __restrict__ rowptr, const int* __restrict__ csr_src,
    const float* __restrict__ att, const float* __restrict__ bias,
    float* __restrict__ out) {
  int n = blockIdx.x * 4 + (threadIdx.x >> 6);
  if (n >= NN) return;
  int lane = threadIdx.x & 63;
  int grp = lane >> 4;        // which of 4 edges in flight
  int cl = lane & 15;         // channel pair index
  uint_t xru = reinterpret_cast<const uint_t*>(xlr + (size_t)n * 64 + 32)[cl];
  float xr0 = bf2f(xru & 0xFFFF), xr1 = bf2f(xru >> 16);
  float2 atv = reinterpret_cast<const float2*>(att)[cl];
  int beg = rowptr[n], end = rowptr[n + 1];
  float m = -3.4e38f, d = 0.f, a0 = 0.f, a1 = 0.f;
  for (int s = beg + grp; s < end; s += 4) {
    int src = csr_src[s];
    uint_t xu = reinterpret_cast<const uint_t*>(xlr + (size_t)src * 64)[cl];
    float x0 = bf2f(xu & 0xFFFF), x1 = bf2f(xu >> 16);
    float e0 = x0 + xr0; e0 = (e0 > 0.f) ? e0 : 0.2f * e0;
    float e1 = x1 + xr1; e1 = (e1 > 0.f) ? e1 : 0.2f * e1;
    float sc = atv.x * e0 + atv.y * e1;
    #pragma unroll
    for (int off = 8; off; off >>= 1) sc += __shfl_xor(sc, off, 64);  // 16-lane sum
    float mn = fmaxf(m, sc);
    float scale = __expf(m - mn);
    float w = __expf(sc - mn);
    a0 = a0 * scale + w * x0;
    a1 = a1 * scale + w * x1;
    d = d * scale + w;
    m = mn;
  }
  // merge the 4 per-group online states (some may be empty; guard via d)
  #pragma unroll
  for (int off = 16; off <= 32; off <<= 1) {
    float mo = __shfl_xor(m, off, 64);
    float doo = __shfl_xor(d, off, 64);
    float c0 = __shfl_xor(a0, off, 64);
    float c1 = __shfl_xor(a1, off, 64);
    if (doo > 0.f) {
      if (d > 0.f) {
        float mn = fmaxf(m, mo);
        float se = __expf(m - mn), so = __expf(mo - mn);
        a0 = a0 * se + c0 * so;
        a1 = a1 * se + c1 * so;
        d = d * se + doo * so;
        m = mn;
      } else {
        a0 = c0; a1 = c1; d = doo; m = mo;
      }
    }
  }
  if (grp == 0) {
    float inv = 1.f / (d + 1e-16f);
    float2 bsv = reinterpret_cast<const float2*>(bias)[cl];
    reinterpret_cast<float2*>(out + (size_t)n * 32)[cl] =
        make_float2(a0 * inv + bsv.x, a1 * inv + bsv.y);
  }
}

extern "C" void kernel_launch(void* const* d_in, const int* in_sizes, int n_in,
                              void* d_out, int out_size, void* d_ws, size_t ws_size,
                              hipStream_t stream) {
  (void)in_sizes; (void)n_in; (void)out_size; (void)ws_size;
  const float* x  = (const float*)d_in[0];
  const int*   ei = (const int*)d_in[1];
  const float *Wl1 = (const float*)d_in[2],  *bl1 = (const float*)d_in[3],
              *Wr1 = (const float*)d_in[4],  *br1 = (const float*)d_in[5],
              *att1 = (const float*)d_in[6], *bias1 = (const float*)d_in[7],
              *g1 = (const float*)d_in[8],   *be1 = (const float*)d_in[9],
              *m1 = (const float*)d_in[10],  *v1 = (const float*)d_in[11];
  const float *Wl2 = (const float*)d_in[12], *bl2 = (const float*)d_in[13],
              *Wr2 = (const float*)d_in[14], *br2 = (const float*)d_in[15],
              *att2 = (const float*)d_in[16], *bias2 = (const float*)d_in[17],
              *g2 = (const float*)d_in[18],  *be2 = (const float*)d_in[19],
              *m2 = (const float*)d_in[20],  *v2 = (const float*)d_in[21];
  const float *Wl3 = (const float*)d_in[22], *bl3 = (const float*)d_in[23],
              *Wr3 = (const float*)d_in[24], *br3 = (const float*)d_in[25],
              *att3 = (const float*)d_in[26], *bias3 = (const float*)d_in[27];
  float* out = (float*)d_out;

  char* p = (char*)d_ws;
  auto alloc = [&](size_t bytes) { char* r = p; p += (bytes + 255) & ~(size_t)255; return r; };
  int*      deg     = (int*)alloc((size_t)NN * 4);
  int*      rowptr  = (int*)alloc((size_t)(NN + 1) * 4);
  int*      cursor  = (int*)alloc((size_t)NN * 4);
  int*      csr_src = (int*)alloc((size_t)ETOT * 4);
  ushort_t* xlr     = (ushort_t*)alloc((size_t)NN * 512 * 2);   // interleaved xl|xr
  ushort_t* hbuf    = (ushort_t*)alloc((size_t)NN * 256 * 2);
  ushort_t* Wb      = (ushort_t*)alloc((size_t)147456 * 2);     // also OOB-read slack for hbuf
  (void)alloc(262144);                                          // tail slack (OOB-read room)

  // CSR by dst
  hipMemsetAsync(deg, 0, (size_t)NN * 4, stream);
  deg_kernel<<<(ETOT + 255) / 256, 256, 0, stream>>>(ei, deg);
  scan_kernel<<<1, 1024, 0, stream>>>(deg, rowptr);
  hipMemcpyAsync(cursor, rowptr, (size_t)NN * 4, hipMemcpyDeviceToDevice, stream);
  fill_kernel<<<(ETOT + 255) / 256, 256, 0, stream>>>(ei, cursor, csr_src);

  // weights -> bf16 (combined [Wl2|Wr2] rows 0..511, [Wl3|Wr3] rows 0..63)
  w2bf_kernel<<<576, 256, 0, stream>>>(Wl2, Wr2, Wl3, Wr3, Wb);

  int nb = (NN + 3) / 4;

  // ---- layer 1: 4 -> 4x64 concat, BN+ELU ----
  lin1_both<<<NN, 256, 0, stream>>>(x, Wl1, bl1, Wr1, br1, xlr);
  fused_agg4<true><<<nb, 256, 0, stream>>>(xlr, rowptr, csr_src, att1, bias1,
                                           g1, be1, m1, v1, hbuf);

  // ---- layer 2: 256 -> 4x64 concat (l and r in one N=512 GEMM), BN+ELU ----
  {
    dim3 g((NN + 63) / 64, 2);   // block tile 64 rows x 256 cols (4 waves on N)
    gemm_mfma<512, 256, 1, 4><<<g, 256, 0, stream>>>(hbuf, Wb, bl2, br2, xlr, NN);
  }
  fused_agg4<true><<<nb, 256, 0, stream>>>(xlr, rowptr, csr_src, att2, bias2,
                                           g2, be2, m2, v2, hbuf);

  // ---- layer 3: 256 -> 32, 1 head (l and r in one N=64 GEMM) ----
  {
    dim3 g((NN + 255) / 256, 1); // block tile 256 rows x 64 cols (4 waves on M)
    gemm_mfma<64, 32, 4, 1><<<g, 256, 0, stream>>>(hbuf, Wb + 131072, bl3, br3, xlr, NN);
  }
  fused_agg3<<<nb, 256, 0, stream>>>(xlr, rowptr, csr_src, att3, bias3, out);
}